// Round 1
// baseline (1086.459 us; speedup 1.0000x reference)
//
#include <hip/hip_runtime.h>

#define N_NODES 50000
#define E_EDGES 800000
#define E_TOT   (E_EDGES + N_NODES)
#define F_INDIM 128
#define NHEAD   4
#define CDIM    64
#define HC      256
#define NGRAPH  512
#define NCLS    10
#define NEG_SLOPE 0.2f

__device__ inline float leakyf(float x) { return x > 0.f ? x : NEG_SLOPE * x; }

// ---------------- CSR build ----------------
__global__ __launch_bounds__(256) void k_init_deg(int* __restrict__ deg) {
  int i = blockIdx.x * 256 + threadIdx.x;
  if (i < N_NODES) deg[i] = 1;  // self-loop
}

__global__ __launch_bounds__(256) void k_hist(const int* __restrict__ ei, int* __restrict__ deg) {
  int e = blockIdx.x * 256 + threadIdx.x;
  if (e < E_EDGES) atomicAdd(&deg[ei[E_EDGES + e]], 1);
}

__global__ __launch_bounds__(256) void k_scan1(const int* __restrict__ deg, int* __restrict__ incl,
                                               int* __restrict__ blksum) {
  __shared__ int s[256];
  int tid = threadIdx.x;
  int i = blockIdx.x * 256 + tid;
  int v = (i < N_NODES) ? deg[i] : 0;
  s[tid] = v;
  __syncthreads();
  for (int d = 1; d < 256; d <<= 1) {
    int t = (tid >= d) ? s[tid - d] : 0;
    __syncthreads();
    s[tid] += t;
    __syncthreads();
  }
  if (i < N_NODES) incl[i] = s[tid];
  if (tid == 255) blksum[blockIdx.x] = s[255];
}

__global__ __launch_bounds__(256) void k_scan2(int* __restrict__ blksum, int nblk) {
  __shared__ int s[256];
  int tid = threadIdx.x;
  int v = (tid < nblk) ? blksum[tid] : 0;
  s[tid] = v;
  __syncthreads();
  for (int d = 1; d < 256; d <<= 1) {
    int t = (tid >= d) ? s[tid - d] : 0;
    __syncthreads();
    s[tid] += t;
    __syncthreads();
  }
  if (tid < nblk) blksum[tid] = s[tid] - v;  // exclusive
}

__global__ __launch_bounds__(256) void k_scan3(const int* __restrict__ deg, int* __restrict__ off,
                                               const int* __restrict__ blksum, int* __restrict__ cursor) {
  int i = blockIdx.x * 256 + threadIdx.x;
  if (i < N_NODES) {
    int excl = off[i] - deg[i] + blksum[blockIdx.x];
    off[i] = excl;
    cursor[i] = excl;
  }
  if (i == 0) off[N_NODES] = E_TOT;
}

__global__ __launch_bounds__(256) void k_fill(const int* __restrict__ ei, int* __restrict__ cursor,
                                              int* __restrict__ csr_src) {
  int idx = blockIdx.x * 256 + threadIdx.x;
  if (idx >= E_TOT) return;
  int s, d;
  if (idx < E_EDGES) { s = ei[idx]; d = ei[E_EDGES + idx]; }
  else               { s = idx - E_EDGES; d = s; }
  int pos = atomicAdd(&cursor[d], 1);
  csr_src[pos] = s;
}

// ---------------- GEMM (f32 VALU, 64x64 tile, 4x4/thread) ----------------
template<int K>
__global__ __launch_bounds__(256) void k_gemm(const float* __restrict__ A, const float* __restrict__ B,
                                              float* __restrict__ Cmat) {
  __shared__ float As[16][64];
  __shared__ float Bs[16][64];
  int tid = threadIdx.x;
  int row0 = blockIdx.x * 64;
  int col0 = blockIdx.y * 64;
  int trow = tid >> 4, tcol = tid & 15;
  int am = tid >> 2, ak = (tid & 3) << 2;
  int bk = tid >> 4, bn = (tid & 15) << 2;
  float c[4][4] = {};
  for (int k0 = 0; k0 < K; k0 += 16) {
    float4 av = make_float4(0.f, 0.f, 0.f, 0.f);
    int ar = row0 + am;
    if (ar < N_NODES) av = *(const float4*)&A[(size_t)ar * K + k0 + ak];
    As[ak + 0][am] = av.x; As[ak + 1][am] = av.y; As[ak + 2][am] = av.z; As[ak + 3][am] = av.w;
    *(float4*)&Bs[bk][bn] = *(const float4*)&B[(size_t)(k0 + bk) * HC + col0 + bn];
    __syncthreads();
#pragma unroll
    for (int kk = 0; kk < 16; ++kk) {
      float4 a4 = *(const float4*)&As[kk][trow << 2];
      float4 b4 = *(const float4*)&Bs[kk][tcol << 2];
      float aa[4] = {a4.x, a4.y, a4.z, a4.w};
      float bb[4] = {b4.x, b4.y, b4.z, b4.w};
#pragma unroll
      for (int i = 0; i < 4; ++i)
#pragma unroll
        for (int j = 0; j < 4; ++j)
          c[i][j] = fmaf(aa[i], bb[j], c[i][j]);
    }
    __syncthreads();
  }
#pragma unroll
  for (int i = 0; i < 4; ++i) {
    int r = row0 + (trow << 2) + i;
    if (r < N_NODES) {
#pragma unroll
      for (int j = 0; j < 4; ++j)
        Cmat[(size_t)r * HC + col0 + (tcol << 2) + j] = c[i][j];
    }
  }
}

// ---------------- attention logits: al[n,h] = sum_c h[n,h,c]*a[h,c] ----------------
__global__ __launch_bounds__(256) void k_attn(const float* __restrict__ h,
                                              const float* __restrict__ a_src, const float* __restrict__ a_dst,
                                              float* __restrict__ al_s, float* __restrict__ al_d) {
  int n = blockIdx.x, tid = threadIdx.x;
  float v = h[(size_t)n * HC + tid];
  float ps = v * a_src[tid];
  float pd = v * a_dst[tid];
#pragma unroll
  for (int o = 32; o > 0; o >>= 1) { ps += __shfl_xor(ps, o); pd += __shfl_xor(pd, o); }
  if ((tid & 63) == 0) {
    al_s[n * 4 + (tid >> 6)] = ps;
    al_d[n * 4 + (tid >> 6)] = pd;
  }
}

// ---------------- GAT aggregation: one block per dst node ----------------
template<bool CONCAT>
__global__ __launch_bounds__(256) void k_aggregate(
    const float* __restrict__ h, const int* __restrict__ off, const int* __restrict__ csr_src,
    const float* __restrict__ al_s, const float* __restrict__ al_d,
    const float* __restrict__ bias, float* __restrict__ out) {
  int d = blockIdx.x;
  int tid = threadIdx.x;
  int head = tid >> 6;
  int lo = off[d];
  int deg = off[d + 1] - lo;

  float4 adv = *(const float4*)&al_d[(size_t)d * 4];
  float ad[4] = {adv.x, adv.y, adv.z, adv.w};

  // phase 1: online segment max/sum per head
  float m[4] = {-1e30f, -1e30f, -1e30f, -1e30f};
  float z[4] = {0.f, 0.f, 0.f, 0.f};
  for (int e = tid; e < deg; e += 256) {
    int s = csr_src[lo + e];
    float4 asv = *(const float4*)&al_s[(size_t)s * 4];
    float as[4] = {asv.x, asv.y, asv.z, asv.w};
#pragma unroll
    for (int hh = 0; hh < 4; ++hh) {
      float ev = leakyf(as[hh] + ad[hh]);
      float mm = fmaxf(m[hh], ev);
      z[hh] = z[hh] * __expf(m[hh] - mm) + __expf(ev - mm);
      m[hh] = mm;
    }
  }
#pragma unroll
  for (int o = 32; o > 0; o >>= 1) {
#pragma unroll
    for (int hh = 0; hh < 4; ++hh) {
      float mo = __shfl_xor(m[hh], o);
      float zo = __shfl_xor(z[hh], o);
      float mm = fmaxf(m[hh], mo);
      z[hh] = z[hh] * __expf(m[hh] - mm) + zo * __expf(mo - mm);
      m[hh] = mm;
    }
  }
  __shared__ float wm[4][4], wz[4][4];
  if ((tid & 63) == 0) {
#pragma unroll
    for (int hh = 0; hh < 4; ++hh) { wm[tid >> 6][hh] = m[hh]; wz[tid >> 6][hh] = z[hh]; }
  }
  __syncthreads();
  float M[4], Zi[4];
#pragma unroll
  for (int hh = 0; hh < 4; ++hh) {
    float mm = -1e30f, zz = 0.f;
#pragma unroll
    for (int w = 0; w < 4; ++w) {
      float mo = wm[w][hh], zo = wz[w][hh];
      float m2 = fmaxf(mm, mo);
      zz = zz * __expf(mm - m2) + zo * __expf(mo - m2);
      mm = m2;
    }
    M[hh] = mm;
    Zi[hh] = 1.f / (zz + 1e-16f);
  }

  // phase 2: weighted gather-accumulate
  __shared__ int src_l[128];
  __shared__ float alpha_l[128 * 4];
  float acc = 0.f;
  for (int base = 0; base < deg; base += 128) {
    int cnt = min(128, deg - base);
    if (tid < cnt) {
      int s = csr_src[lo + base + tid];
      src_l[tid] = s;
      float4 asv = *(const float4*)&al_s[(size_t)s * 4];
      float as[4] = {asv.x, asv.y, asv.z, asv.w};
#pragma unroll
      for (int hh = 0; hh < 4; ++hh)
        alpha_l[tid * 4 + hh] = __expf(leakyf(as[hh] + ad[hh]) - M[hh]) * Zi[hh];
    }
    __syncthreads();
    for (int e = 0; e < cnt; ++e) {
      acc = fmaf(alpha_l[e * 4 + head], h[(size_t)src_l[e] * HC + tid], acc);
    }
    __syncthreads();
  }

  if (CONCAT) {
    out[(size_t)d * HC + tid] = fmaxf(acc + bias[tid], 0.f);
  } else {
    __shared__ float hs[256];
    hs[tid] = acc;
    __syncthreads();
    if (tid < 64) {
      float v = (hs[tid] + hs[tid + 64] + hs[tid + 128] + hs[tid + 192]) * 0.25f;
      out[(size_t)d * CDIM + tid] = fmaxf(v + bias[tid], 0.f);
    }
  }
}

// ---------------- global mean pool + final linear ----------------
__device__ inline int lower_bound_i(const int* __restrict__ a, int n, int key) {
  int lo = 0, hi = n;
  while (lo < hi) { int mid = (lo + hi) >> 1; if (a[mid] < key) lo = mid + 1; else hi = mid; }
  return lo;
}

__global__ __launch_bounds__(256) void k_pool(const float* __restrict__ x, const int* __restrict__ batch,
                                              const float* __restrict__ Wl, const float* __restrict__ bl,
                                              float* __restrict__ out) {
  int g = blockIdx.x, tid = threadIdx.x;
  int lo = lower_bound_i(batch, N_NODES, g);
  int hi = lower_bound_i(batch, N_NODES, g + 1);
  int c = tid & 63, sl = tid >> 6;
  float acc = 0.f;
  for (int n = lo + sl; n < hi; n += 4)
    acc += x[(size_t)n * CDIM + c];
  __shared__ float s[256];
  __shared__ float pooled[64];
  s[tid] = acc;
  __syncthreads();
  if (tid < 64) {
    float cnt = fmaxf((float)(hi - lo), 1.f);
    pooled[tid] = (s[tid] + s[tid + 64] + s[tid + 128] + s[tid + 192]) / cnt;
  }
  __syncthreads();
  if (tid < NCLS) {
    float o = bl[tid];
    for (int cc = 0; cc < CDIM; ++cc)
      o = fmaf(pooled[cc], Wl[cc * NCLS + tid], o);
    out[g * NCLS + tid] = o;
  }
}

extern "C" void kernel_launch(void* const* d_in, const int* in_sizes, int n_in,
                              void* d_out, int out_size, void* d_ws, size_t ws_size,
                              hipStream_t stream) {
  const float* x     = (const float*)d_in[0];
  const int*   ei    = (const int*)d_in[1];
  const int*   batch = (const int*)d_in[2];
  const float* W1  = (const float*)d_in[3];
  const float* as1 = (const float*)d_in[4];
  const float* ad1 = (const float*)d_in[5];
  const float* b1  = (const float*)d_in[6];
  const float* W2  = (const float*)d_in[7];
  const float* as2 = (const float*)d_in[8];
  const float* ad2 = (const float*)d_in[9];
  const float* b2  = (const float*)d_in[10];
  const float* W3  = (const float*)d_in[11];
  const float* as3 = (const float*)d_in[12];
  const float* ad3 = (const float*)d_in[13];
  const float* b3  = (const float*)d_in[14];
  const float* Wl  = (const float*)d_in[15];
  const float* bl  = (const float*)d_in[16];
  float* out = (float*)d_out;

  char* ws = (char*)d_ws;
  size_t o = 0;
  auto alloc = [&](size_t bytes) -> void* {
    void* p = ws + o;
    o += (bytes + 255) & ~(size_t)255;
    return p;
  };
  float* bufA  = (float*)alloc((size_t)N_NODES * HC * 4);
  float* bufB  = (float*)alloc((size_t)N_NODES * HC * 4);
  float* al_s  = (float*)alloc((size_t)N_NODES * 4 * 4);
  float* al_d  = (float*)alloc((size_t)N_NODES * 4 * 4);
  int*   deg   = (int*)alloc((size_t)N_NODES * 4);
  int*   off   = (int*)alloc((size_t)(N_NODES + 1) * 4);
  int*   cursor= (int*)alloc((size_t)N_NODES * 4);
  int*   blksum= (int*)alloc(1024);
  int*   csr   = (int*)alloc((size_t)E_TOT * 4);

  int nblk = (N_NODES + 255) / 256;  // 196
  k_init_deg<<<nblk, 256, 0, stream>>>(deg);
  k_hist<<<(E_EDGES + 255) / 256, 256, 0, stream>>>(ei, deg);
  k_scan1<<<nblk, 256, 0, stream>>>(deg, off, blksum);
  k_scan2<<<1, 256, 0, stream>>>(blksum, nblk);
  k_scan3<<<nblk, 256, 0, stream>>>(deg, off, blksum, cursor);
  k_fill<<<(E_TOT + 255) / 256, 256, 0, stream>>>(ei, cursor, csr);

  dim3 ggrid((N_NODES + 63) / 64, HC / 64);
  // conv1
  k_gemm<F_INDIM><<<ggrid, 256, 0, stream>>>(x, W1, bufA);
  k_attn<<<N_NODES, 256, 0, stream>>>(bufA, as1, ad1, al_s, al_d);
  k_aggregate<true><<<N_NODES, 256, 0, stream>>>(bufA, off, csr, al_s, al_d, b1, bufB);
  // conv2
  k_gemm<HC><<<ggrid, 256, 0, stream>>>(bufB, W2, bufA);
  k_attn<<<N_NODES, 256, 0, stream>>>(bufA, as2, ad2, al_s, al_d);
  k_aggregate<true><<<N_NODES, 256, 0, stream>>>(bufA, off, csr, al_s, al_d, b2, bufB);
  // conv3
  k_gemm<HC><<<ggrid, 256, 0, stream>>>(bufB, W3, bufA);
  k_attn<<<N_NODES, 256, 0, stream>>>(bufA, as3, ad3, al_s, al_d);
  k_aggregate<false><<<N_NODES, 256, 0, stream>>>(bufA, off, csr, al_s, al_d, b3, bufB);
  // pool + linear
  k_pool<<<NGRAPH, 256, 0, stream>>>(bufB, batch, Wl, bl, out);
}

// Round 2
// 1064.117 us; speedup vs baseline: 1.0210x; 1.0210x over previous
//
#include <hip/hip_runtime.h>

#define N_NODES 50000
#define E_EDGES 800000
#define E_TOT   (E_EDGES + N_NODES)
#define F_INDIM 128
#define NHEAD   4
#define CDIM    64
#define HC      256
#define NGRAPH  512
#define NCLS    10
#define NEG_SLOPE 0.2f

__device__ inline float leakyf(float x) { return x > 0.f ? x : NEG_SLOPE * x; }

// ---------------- CSR build ----------------
__global__ __launch_bounds__(256) void k_init_deg(int* __restrict__ deg) {
  int i = blockIdx.x * 256 + threadIdx.x;
  if (i < N_NODES) deg[i] = 1;  // self-loop
}

__global__ __launch_bounds__(256) void k_hist(const int* __restrict__ ei, int* __restrict__ deg) {
  int e = blockIdx.x * 256 + threadIdx.x;
  if (e < E_EDGES) atomicAdd(&deg[ei[E_EDGES + e]], 1);
}

__global__ __launch_bounds__(256) void k_scan1(const int* __restrict__ deg, int* __restrict__ incl,
                                               int* __restrict__ blksum) {
  __shared__ int s[256];
  int tid = threadIdx.x;
  int i = blockIdx.x * 256 + tid;
  int v = (i < N_NODES) ? deg[i] : 0;
  s[tid] = v;
  __syncthreads();
  for (int d = 1; d < 256; d <<= 1) {
    int t = (tid >= d) ? s[tid - d] : 0;
    __syncthreads();
    s[tid] += t;
    __syncthreads();
  }
  if (i < N_NODES) incl[i] = s[tid];
  if (tid == 255) blksum[blockIdx.x] = s[255];
}

__global__ __launch_bounds__(256) void k_scan2(int* __restrict__ blksum, int nblk) {
  __shared__ int s[256];
  int tid = threadIdx.x;
  int v = (tid < nblk) ? blksum[tid] : 0;
  s[tid] = v;
  __syncthreads();
  for (int d = 1; d < 256; d <<= 1) {
    int t = (tid >= d) ? s[tid - d] : 0;
    __syncthreads();
    s[tid] += t;
    __syncthreads();
  }
  if (tid < nblk) blksum[tid] = s[tid] - v;  // exclusive
}

__global__ __launch_bounds__(256) void k_scan3(const int* __restrict__ deg, int* __restrict__ off,
                                               const int* __restrict__ blksum, int* __restrict__ cursor) {
  int i = blockIdx.x * 256 + threadIdx.x;
  if (i < N_NODES) {
    int excl = off[i] - deg[i] + blksum[blockIdx.x];
    off[i] = excl;
    cursor[i] = excl;
  }
  if (i == 0) off[N_NODES] = E_TOT;
}

__global__ __launch_bounds__(256) void k_fill(const int* __restrict__ ei, int* __restrict__ cursor,
                                              int* __restrict__ csr_src) {
  int idx = blockIdx.x * 256 + threadIdx.x;
  if (idx >= E_TOT) return;
  int s, d;
  if (idx < E_EDGES) { s = ei[idx]; d = ei[E_EDGES + idx]; }
  else               { s = idx - E_EDGES; d = s; }
  int pos = atomicAdd(&cursor[d], 1);
  csr_src[pos] = s;
}

// ---------------- GEMM (f32 VALU, 64x64 tile, 4x4/thread) ----------------
template<int K>
__global__ __launch_bounds__(256) void k_gemm(const float* __restrict__ A, const float* __restrict__ B,
                                              float* __restrict__ Cmat) {
  __shared__ float As[16][64];
  __shared__ float Bs[16][64];
  int tid = threadIdx.x;
  int row0 = blockIdx.x * 64;
  int col0 = blockIdx.y * 64;
  int trow = tid >> 4, tcol = tid & 15;
  int am = tid >> 2, ak = (tid & 3) << 2;
  int bk = tid >> 4, bn = (tid & 15) << 2;
  float c[4][4] = {};
  for (int k0 = 0; k0 < K; k0 += 16) {
    float4 av = make_float4(0.f, 0.f, 0.f, 0.f);
    int ar = row0 + am;
    if (ar < N_NODES) av = *(const float4*)&A[(size_t)ar * K + k0 + ak];
    As[ak + 0][am] = av.x; As[ak + 1][am] = av.y; As[ak + 2][am] = av.z; As[ak + 3][am] = av.w;
    *(float4*)&Bs[bk][bn] = *(const float4*)&B[(size_t)(k0 + bk) * HC + col0 + bn];
    __syncthreads();
#pragma unroll
    for (int kk = 0; kk < 16; ++kk) {
      float4 a4 = *(const float4*)&As[kk][trow << 2];
      float4 b4 = *(const float4*)&Bs[kk][tcol << 2];
      float aa[4] = {a4.x, a4.y, a4.z, a4.w};
      float bb[4] = {b4.x, b4.y, b4.z, b4.w};
#pragma unroll
      for (int i = 0; i < 4; ++i)
#pragma unroll
        for (int j = 0; j < 4; ++j)
          c[i][j] = fmaf(aa[i], bb[j], c[i][j]);
    }
    __syncthreads();
  }
#pragma unroll
  for (int i = 0; i < 4; ++i) {
    int r = row0 + (trow << 2) + i;
    if (r < N_NODES) {
#pragma unroll
      for (int j = 0; j < 4; ++j)
        Cmat[(size_t)r * HC + col0 + (tcol << 2) + j] = c[i][j];
    }
  }
}

// ---------------- attention logits: al[n,h] = sum_c h[n,h,c]*a[h,c] ----------------
__global__ __launch_bounds__(256) void k_attn(const float* __restrict__ h,
                                              const float* __restrict__ a_src, const float* __restrict__ a_dst,
                                              float* __restrict__ al_s, float* __restrict__ al_d) {
  int n = blockIdx.x, tid = threadIdx.x;
  float v = h[(size_t)n * HC + tid];
  float ps = v * a_src[tid];
  float pd = v * a_dst[tid];
#pragma unroll
  for (int o = 32; o > 0; o >>= 1) { ps += __shfl_xor(ps, o); pd += __shfl_xor(pd, o); }
  if ((tid & 63) == 0) {
    al_s[n * 4 + (tid >> 6)] = ps;
    al_d[n * 4 + (tid >> 6)] = pd;
  }
}

// ---------------- GAT aggregation: one block per dst node ----------------
// 256 threads = 4 edge-slots x 64 channel-groups (float4 per group).
template<bool CONCAT>
__global__ __launch_bounds__(256) void k_aggregate(
    const float* __restrict__ h, const int* __restrict__ off, const int* __restrict__ csr_src,
    const float* __restrict__ al_s, const float* __restrict__ al_d,
    const float* __restrict__ bias, float* __restrict__ out) {
  int d = blockIdx.x;
  int tid = threadIdx.x;
  int slot = tid >> 6;      // 0..3 (wave id)
  int cg = tid & 63;        // channel group: channels cg*4 .. cg*4+3
  int head = cg >> 4;       // 4 heads x 16 groups
  int lo = off[d];
  int deg = off[d + 1] - lo;

  float4 adv = *(const float4*)&al_d[(size_t)d * 4];
  float ad[4] = {adv.x, adv.y, adv.z, adv.w};

  // phase 1: online segment max/sum per head (edge-strided over all 256 threads)
  float m[4] = {-1e30f, -1e30f, -1e30f, -1e30f};
  float z[4] = {0.f, 0.f, 0.f, 0.f};
  for (int e = tid; e < deg; e += 256) {
    int s = csr_src[lo + e];
    float4 asv = *(const float4*)&al_s[(size_t)s * 4];
    float as[4] = {asv.x, asv.y, asv.z, asv.w};
#pragma unroll
    for (int hh = 0; hh < 4; ++hh) {
      float ev = leakyf(as[hh] + ad[hh]);
      float mm = fmaxf(m[hh], ev);
      z[hh] = z[hh] * __expf(m[hh] - mm) + __expf(ev - mm);
      m[hh] = mm;
    }
  }
#pragma unroll
  for (int o = 32; o > 0; o >>= 1) {
#pragma unroll
    for (int hh = 0; hh < 4; ++hh) {
      float mo = __shfl_xor(m[hh], o);
      float zo = __shfl_xor(z[hh], o);
      float mm = fmaxf(m[hh], mo);
      z[hh] = z[hh] * __expf(m[hh] - mm) + zo * __expf(mo - mm);
      m[hh] = mm;
    }
  }
  __shared__ float wm[4][4], wz[4][4];
  if ((tid & 63) == 0) {
#pragma unroll
    for (int hh = 0; hh < 4; ++hh) { wm[tid >> 6][hh] = m[hh]; wz[tid >> 6][hh] = z[hh]; }
  }
  __syncthreads();
  float M[4], Zi[4];
#pragma unroll
  for (int hh = 0; hh < 4; ++hh) {
    float mm = -1e30f, zz = 0.f;
#pragma unroll
    for (int w = 0; w < 4; ++w) {
      float mo = wm[w][hh], zo = wz[w][hh];
      float m2 = fmaxf(mm, mo);
      zz = zz * __expf(mm - m2) + zo * __expf(mo - m2);
      mm = m2;
    }
    M[hh] = mm;
    Zi[hh] = 1.f / (zz + 1e-16f);
  }

  // phase 2: weighted gather-accumulate, 4 edges in flight, float4 per thread
  __shared__ int src_l[64];
  __shared__ float alpha_l[4][64];   // [head][edge]
  float4 acc = make_float4(0.f, 0.f, 0.f, 0.f);
  for (int base = 0; base < deg; base += 64) {
    int cnt = min(64, deg - base);
    if (tid < cnt) {
      int s = csr_src[lo + base + tid];
      src_l[tid] = s;
      float4 asv = *(const float4*)&al_s[(size_t)s * 4];
      float as[4] = {asv.x, asv.y, asv.z, asv.w};
#pragma unroll
      for (int hh = 0; hh < 4; ++hh)
        alpha_l[hh][tid] = __expf(leakyf(as[hh] + ad[hh]) - M[hh]) * Zi[hh];
    }
    __syncthreads();
    for (int e = slot; e < cnt; e += 4) {
      int s = src_l[e];
      float a = alpha_l[head][e];
      float4 hv = *(const float4*)&h[(size_t)s * HC + (cg << 2)];
      acc.x = fmaf(a, hv.x, acc.x);
      acc.y = fmaf(a, hv.y, acc.y);
      acc.z = fmaf(a, hv.z, acc.z);
      acc.w = fmaf(a, hv.w, acc.w);
    }
    __syncthreads();
  }

  // reduce across the 4 edge-slots
  __shared__ float4 part[4][64];
  part[slot][cg] = acc;
  __syncthreads();
  if (CONCAT) {
    if (tid < 64) {
      float4 v0 = part[0][tid], v1 = part[1][tid], v2 = part[2][tid], v3 = part[3][tid];
      float4 bb = *(const float4*)&bias[tid << 2];
      float4 v;
      v.x = fmaxf(v0.x + v1.x + v2.x + v3.x + bb.x, 0.f);
      v.y = fmaxf(v0.y + v1.y + v2.y + v3.y + bb.y, 0.f);
      v.z = fmaxf(v0.z + v1.z + v2.z + v3.z + bb.z, 0.f);
      v.w = fmaxf(v0.w + v1.w + v2.w + v3.w + bb.w, 0.f);
      *(float4*)&out[(size_t)d * HC + (tid << 2)] = v;
    }
  } else {
    __shared__ float hs[256];
    if (tid < 64) {
      float4 v0 = part[0][tid], v1 = part[1][tid], v2 = part[2][tid], v3 = part[3][tid];
      hs[(tid << 2) + 0] = v0.x + v1.x + v2.x + v3.x;
      hs[(tid << 2) + 1] = v0.y + v1.y + v2.y + v3.y;
      hs[(tid << 2) + 2] = v0.z + v1.z + v2.z + v3.z;
      hs[(tid << 2) + 3] = v0.w + v1.w + v2.w + v3.w;
    }
    __syncthreads();
    if (tid < 64) {
      float v = (hs[tid] + hs[tid + 64] + hs[tid + 128] + hs[tid + 192]) * 0.25f;
      out[(size_t)d * CDIM + tid] = fmaxf(v + bias[tid], 0.f);
    }
  }
}

// ---------------- global mean pool + final linear ----------------
__device__ inline int lower_bound_i(const int* __restrict__ a, int n, int key) {
  int lo = 0, hi = n;
  while (lo < hi) { int mid = (lo + hi) >> 1; if (a[mid] < key) lo = mid + 1; else hi = mid; }
  return lo;
}

__global__ __launch_bounds__(256) void k_pool(const float* __restrict__ x, const int* __restrict__ batch,
                                              const float* __restrict__ Wl, const float* __restrict__ bl,
                                              float* __restrict__ out) {
  int g = blockIdx.x, tid = threadIdx.x;
  int lo = lower_bound_i(batch, N_NODES, g);
  int hi = lower_bound_i(batch, N_NODES, g + 1);
  int c = tid & 63, sl = tid >> 6;
  float acc = 0.f;
  for (int n = lo + sl; n < hi; n += 4)
    acc += x[(size_t)n * CDIM + c];
  __shared__ float s[256];
  __shared__ float pooled[64];
  s[tid] = acc;
  __syncthreads();
  if (tid < 64) {
    float cnt = fmaxf((float)(hi - lo), 1.f);
    pooled[tid] = (s[tid] + s[tid + 64] + s[tid + 128] + s[tid + 192]) / cnt;
  }
  __syncthreads();
  if (tid < NCLS) {
    float o = bl[tid];
    for (int cc = 0; cc < CDIM; ++cc)
      o = fmaf(pooled[cc], Wl[cc * NCLS + tid], o);
    out[g * NCLS + tid] = o;
  }
}

extern "C" void kernel_launch(void* const* d_in, const int* in_sizes, int n_in,
                              void* d_out, int out_size, void* d_ws, size_t ws_size,
                              hipStream_t stream) {
  const float* x     = (const float*)d_in[0];
  const int*   ei    = (const int*)d_in[1];
  const int*   batch = (const int*)d_in[2];
  const float* W1  = (const float*)d_in[3];
  const float* as1 = (const float*)d_in[4];
  const float* ad1 = (const float*)d_in[5];
  const float* b1  = (const float*)d_in[6];
  const float* W2  = (const float*)d_in[7];
  const float* as2 = (const float*)d_in[8];
  const float* ad2 = (const float*)d_in[9];
  const float* b2  = (const float*)d_in[10];
  const float* W3  = (const float*)d_in[11];
  const float* as3 = (const float*)d_in[12];
  const float* ad3 = (const float*)d_in[13];
  const float* b3  = (const float*)d_in[14];
  const float* Wl  = (const float*)d_in[15];
  const float* bl  = (const float*)d_in[16];
  float* out = (float*)d_out;

  char* ws = (char*)d_ws;
  size_t o = 0;
  auto alloc = [&](size_t bytes) -> void* {
    void* p = ws + o;
    o += (bytes + 255) & ~(size_t)255;
    return p;
  };
  float* bufA  = (float*)alloc((size_t)N_NODES * HC * 4);
  float* bufB  = (float*)alloc((size_t)N_NODES * HC * 4);
  float* al_s  = (float*)alloc((size_t)N_NODES * 4 * 4);
  float* al_d  = (float*)alloc((size_t)N_NODES * 4 * 4);
  int*   deg   = (int*)alloc((size_t)N_NODES * 4);
  int*   off   = (int*)alloc((size_t)(N_NODES + 1) * 4);
  int*   cursor= (int*)alloc((size_t)N_NODES * 4);
  int*   blksum= (int*)alloc(1024);
  int*   csr   = (int*)alloc((size_t)E_TOT * 4);

  int nblk = (N_NODES + 255) / 256;  // 196
  k_init_deg<<<nblk, 256, 0, stream>>>(deg);
  k_hist<<<(E_EDGES + 255) / 256, 256, 0, stream>>>(ei, deg);
  k_scan1<<<nblk, 256, 0, stream>>>(deg, off, blksum);
  k_scan2<<<1, 256, 0, stream>>>(blksum, nblk);
  k_scan3<<<nblk, 256, 0, stream>>>(deg, off, blksum, cursor);
  k_fill<<<(E_TOT + 255) / 256, 256, 0, stream>>>(ei, cursor, csr);

  dim3 ggrid((N_NODES + 63) / 64, HC / 64);
  // conv1
  k_gemm<F_INDIM><<<ggrid, 256, 0, stream>>>(x, W1, bufA);
  k_attn<<<N_NODES, 256, 0, stream>>>(bufA, as1, ad1, al_s, al_d);
  k_aggregate<true><<<N_NODES, 256, 0, stream>>>(bufA, off, csr, al_s, al_d, b1, bufB);
  // conv2
  k_gemm<HC><<<ggrid, 256, 0, stream>>>(bufB, W2, bufA);
  k_attn<<<N_NODES, 256, 0, stream>>>(bufA, as2, ad2, al_s, al_d);
  k_aggregate<true><<<N_NODES, 256, 0, stream>>>(bufA, off, csr, al_s, al_d, b2, bufB);
  // conv3
  k_gemm<HC><<<ggrid, 256, 0, stream>>>(bufB, W3, bufA);
  k_attn<<<N_NODES, 256, 0, stream>>>(bufA, as3, ad3, al_s, al_d);
  k_aggregate<false><<<N_NODES, 256, 0, stream>>>(bufA, off, csr, al_s, al_d, b3, bufB);
  // pool + linear
  k_pool<<<NGRAPH, 256, 0, stream>>>(bufB, batch, Wl, bl, out);
}

// Round 3
// 776.385 us; speedup vs baseline: 1.3994x; 1.3706x over previous
//
#include <hip/hip_runtime.h>

#define N_NODES 50000
#define E_EDGES 800000
#define E_TOT   (E_EDGES + N_NODES)
#define F_INDIM 128
#define NHEAD   4
#define CDIM    64
#define HC      256
#define NGRAPH  512
#define NCLS    10
#define NEG_SLOPE 0.2f

__device__ inline float leakyf(float x) { return x > 0.f ? x : NEG_SLOPE * x; }

// ---------------- CSR build ----------------
__global__ __launch_bounds__(256) void k_init_deg(int* __restrict__ deg) {
  int i = blockIdx.x * 256 + threadIdx.x;
  if (i < N_NODES) deg[i] = 1;  // self-loop
}

__global__ __launch_bounds__(256) void k_hist(const int* __restrict__ ei, int* __restrict__ deg) {
  int e = blockIdx.x * 256 + threadIdx.x;
  if (e < E_EDGES) atomicAdd(&deg[ei[E_EDGES + e]], 1);
}

__global__ __launch_bounds__(256) void k_scan1(const int* __restrict__ deg, int* __restrict__ incl,
                                               int* __restrict__ blksum) {
  __shared__ int s[256];
  int tid = threadIdx.x;
  int i = blockIdx.x * 256 + tid;
  int v = (i < N_NODES) ? deg[i] : 0;
  s[tid] = v;
  __syncthreads();
  for (int d = 1; d < 256; d <<= 1) {
    int t = (tid >= d) ? s[tid - d] : 0;
    __syncthreads();
    s[tid] += t;
    __syncthreads();
  }
  if (i < N_NODES) incl[i] = s[tid];
  if (tid == 255) blksum[blockIdx.x] = s[255];
}

__global__ __launch_bounds__(256) void k_scan2(int* __restrict__ blksum, int nblk) {
  __shared__ int s[256];
  int tid = threadIdx.x;
  int v = (tid < nblk) ? blksum[tid] : 0;
  s[tid] = v;
  __syncthreads();
  for (int d = 1; d < 256; d <<= 1) {
    int t = (tid >= d) ? s[tid - d] : 0;
    __syncthreads();
    s[tid] += t;
    __syncthreads();
  }
  if (tid < nblk) blksum[tid] = s[tid] - v;  // exclusive
}

__global__ __launch_bounds__(256) void k_scan3(const int* __restrict__ deg, int* __restrict__ off,
                                               const int* __restrict__ blksum, int* __restrict__ cursor) {
  int i = blockIdx.x * 256 + threadIdx.x;
  if (i < N_NODES) {
    int excl = off[i] - deg[i] + blksum[blockIdx.x];
    off[i] = excl;
    cursor[i] = excl;
  }
  if (i == 0) off[N_NODES] = E_TOT;
}

__global__ __launch_bounds__(256) void k_fill(const int* __restrict__ ei, int* __restrict__ cursor,
                                              int* __restrict__ csr_src) {
  int idx = blockIdx.x * 256 + threadIdx.x;
  if (idx >= E_TOT) return;
  int s, d;
  if (idx < E_EDGES) { s = ei[idx]; d = ei[E_EDGES + idx]; }
  else               { s = idx - E_EDGES; d = s; }
  int pos = atomicAdd(&cursor[d], 1);
  csr_src[pos] = s;
}

// ---------------- GEMM (f32 VALU, 64x64 tile, 4x4/thread) ----------------
template<int K>
__global__ __launch_bounds__(256) void k_gemm(const float* __restrict__ A, const float* __restrict__ B,
                                              float* __restrict__ Cmat) {
  __shared__ float As[16][64];
  __shared__ float Bs[16][64];
  int tid = threadIdx.x;
  int row0 = blockIdx.x * 64;
  int col0 = blockIdx.y * 64;
  int trow = tid >> 4, tcol = tid & 15;
  int am = tid >> 2, ak = (tid & 3) << 2;
  int bk = tid >> 4, bn = (tid & 15) << 2;
  float c[4][4] = {};
  for (int k0 = 0; k0 < K; k0 += 16) {
    float4 av = make_float4(0.f, 0.f, 0.f, 0.f);
    int ar = row0 + am;
    if (ar < N_NODES) av = *(const float4*)&A[(size_t)ar * K + k0 + ak];
    As[ak + 0][am] = av.x; As[ak + 1][am] = av.y; As[ak + 2][am] = av.z; As[ak + 3][am] = av.w;
    *(float4*)&Bs[bk][bn] = *(const float4*)&B[(size_t)(k0 + bk) * HC + col0 + bn];
    __syncthreads();
#pragma unroll
    for (int kk = 0; kk < 16; ++kk) {
      float4 a4 = *(const float4*)&As[kk][trow << 2];
      float4 b4 = *(const float4*)&Bs[kk][tcol << 2];
      float aa[4] = {a4.x, a4.y, a4.z, a4.w};
      float bb[4] = {b4.x, b4.y, b4.z, b4.w};
#pragma unroll
      for (int i = 0; i < 4; ++i)
#pragma unroll
        for (int j = 0; j < 4; ++j)
          c[i][j] = fmaf(aa[i], bb[j], c[i][j]);
    }
    __syncthreads();
  }
#pragma unroll
  for (int i = 0; i < 4; ++i) {
    int r = row0 + (trow << 2) + i;
    if (r < N_NODES) {
#pragma unroll
      for (int j = 0; j < 4; ++j)
        Cmat[(size_t)r * HC + col0 + (tcol << 2) + j] = c[i][j];
    }
  }
}

// ---------------- attention logits: one wave per node ----------------
__global__ __launch_bounds__(256) void k_attn(const float* __restrict__ h,
                                              const float* __restrict__ a_src, const float* __restrict__ a_dst,
                                              float* __restrict__ al_s, float* __restrict__ al_d) {
  int tid = threadIdx.x;
  int lane = tid & 63;
  int n = blockIdx.x * 4 + (tid >> 6);
  float4 v  = *(const float4*)&h[(size_t)n * HC + (lane << 2)];
  float4 as = *(const float4*)&a_src[lane << 2];
  float4 ad = *(const float4*)&a_dst[lane << 2];
  float ps = v.x * as.x + v.y * as.y + v.z * as.z + v.w * as.w;
  float pd = v.x * ad.x + v.y * ad.y + v.z * ad.z + v.w * ad.w;
#pragma unroll
  for (int o = 1; o < 16; o <<= 1) { ps += __shfl_xor(ps, o); pd += __shfl_xor(pd, o); }
  if ((lane & 15) == 0) {
    al_s[n * 4 + (lane >> 4)] = ps;
    al_d[n * 4 + (lane >> 4)] = pd;
  }
}

// ---------------- GAT aggregation: one WAVE per dst node ----------------
template<bool CONCAT>
__global__ __launch_bounds__(256) void k_aggregate(
    const float* __restrict__ h, const int* __restrict__ off, const int* __restrict__ csr_src,
    const float* __restrict__ al_s, const float* __restrict__ al_d,
    const float* __restrict__ bias, float* __restrict__ out) {
  __shared__ float s_alpha[4][64][4];
  __shared__ int   s_src[4][64];
  int tid = threadIdx.x;
  int wv = tid >> 6;
  int lane = tid & 63;
  int head = lane >> 4;
  int d = blockIdx.x * 4 + wv;

  int lo  = off[d];
  int deg = off[d + 1] - lo;

  float4 adv = *(const float4*)&al_d[(size_t)d * 4];

  // pass A: per-lane max over strided edges; cache first edge in regs
  float m0 = -1e30f, m1 = -1e30f, m2 = -1e30f, m3 = -1e30f;
  int s0 = 0;
  float e00 = -1e30f, e01 = -1e30f, e02 = -1e30f, e03 = -1e30f;
  for (int e = lane; e < deg; e += 64) {
    int s = csr_src[lo + e];
    float4 asv = *(const float4*)&al_s[(size_t)s * 4];
    float v0 = leakyf(asv.x + adv.x);
    float v1 = leakyf(asv.y + adv.y);
    float v2 = leakyf(asv.z + adv.z);
    float v3 = leakyf(asv.w + adv.w);
    if (e == lane) { s0 = s; e00 = v0; e01 = v1; e02 = v2; e03 = v3; }
    m0 = fmaxf(m0, v0); m1 = fmaxf(m1, v1); m2 = fmaxf(m2, v2); m3 = fmaxf(m3, v3);
  }
#pragma unroll
  for (int o = 1; o < 64; o <<= 1) {
    m0 = fmaxf(m0, __shfl_xor(m0, o));
    m1 = fmaxf(m1, __shfl_xor(m1, o));
    m2 = fmaxf(m2, __shfl_xor(m2, o));
    m3 = fmaxf(m3, __shfl_xor(m3, o));
  }
  // pass B: sum of exp (first edge from registers; extra edges rare)
  float p00 = 0.f, p01 = 0.f, p02 = 0.f, p03 = 0.f;
  if (lane < deg) {
    p00 = __expf(e00 - m0); p01 = __expf(e01 - m1);
    p02 = __expf(e02 - m2); p03 = __expf(e03 - m3);
  }
  float z0 = p00, z1 = p01, z2 = p02, z3 = p03;
  for (int e = lane + 64; e < deg; e += 64) {  // rare
    int s = csr_src[lo + e];
    float4 asv = *(const float4*)&al_s[(size_t)s * 4];
    z0 += __expf(leakyf(asv.x + adv.x) - m0);
    z1 += __expf(leakyf(asv.y + adv.y) - m1);
    z2 += __expf(leakyf(asv.z + adv.z) - m2);
    z3 += __expf(leakyf(asv.w + adv.w) - m3);
  }
#pragma unroll
  for (int o = 1; o < 64; o <<= 1) {
    z0 += __shfl_xor(z0, o); z1 += __shfl_xor(z1, o);
    z2 += __shfl_xor(z2, o); z3 += __shfl_xor(z3, o);
  }
  float zi0 = 1.f / (z0 + 1e-16f), zi1 = 1.f / (z1 + 1e-16f);
  float zi2 = 1.f / (z2 + 1e-16f), zi3 = 1.f / (z3 + 1e-16f);

  s_alpha[wv][lane][0] = p00 * zi0;
  s_alpha[wv][lane][1] = p01 * zi1;
  s_alpha[wv][lane][2] = p02 * zi2;
  s_alpha[wv][lane][3] = p03 * zi3;
  s_src[wv][lane] = s0;
  __syncthreads();

  // phase 3: gather, 4 edges in flight
  int cg4 = lane << 2;
  int dcap = min(deg, 64);
  float4 acc = make_float4(0.f, 0.f, 0.f, 0.f);
  int e = 0;
  for (; e + 4 <= dcap; e += 4) {
    int sa = s_src[wv][e + 0], sb = s_src[wv][e + 1];
    int sc = s_src[wv][e + 2], sd = s_src[wv][e + 3];
    float aa = s_alpha[wv][e + 0][head], ab = s_alpha[wv][e + 1][head];
    float ac = s_alpha[wv][e + 2][head], ax = s_alpha[wv][e + 3][head];
    float4 ha = *(const float4*)&h[(size_t)sa * HC + cg4];
    float4 hb = *(const float4*)&h[(size_t)sb * HC + cg4];
    float4 hc = *(const float4*)&h[(size_t)sc * HC + cg4];
    float4 hd = *(const float4*)&h[(size_t)sd * HC + cg4];
    acc.x = fmaf(aa, ha.x, acc.x); acc.y = fmaf(aa, ha.y, acc.y);
    acc.z = fmaf(aa, ha.z, acc.z); acc.w = fmaf(aa, ha.w, acc.w);
    acc.x = fmaf(ab, hb.x, acc.x); acc.y = fmaf(ab, hb.y, acc.y);
    acc.z = fmaf(ab, hb.z, acc.z); acc.w = fmaf(ab, hb.w, acc.w);
    acc.x = fmaf(ac, hc.x, acc.x); acc.y = fmaf(ac, hc.y, acc.y);
    acc.z = fmaf(ac, hc.z, acc.z); acc.w = fmaf(ac, hc.w, acc.w);
    acc.x = fmaf(ax, hd.x, acc.x); acc.y = fmaf(ax, hd.y, acc.y);
    acc.z = fmaf(ax, hd.z, acc.z); acc.w = fmaf(ax, hd.w, acc.w);
  }
  for (; e < dcap; ++e) {
    int s = s_src[wv][e];
    float a = s_alpha[wv][e][head];
    float4 hv = *(const float4*)&h[(size_t)s * HC + cg4];
    acc.x = fmaf(a, hv.x, acc.x); acc.y = fmaf(a, hv.y, acc.y);
    acc.z = fmaf(a, hv.z, acc.z); acc.w = fmaf(a, hv.w, acc.w);
  }
  if (deg > 64) {  // rare slow path: recompute alpha for edges >= 64
    for (int e2 = 64; e2 < deg; ++e2) {
      int s = csr_src[lo + e2];
      float4 asv = *(const float4*)&al_s[(size_t)s * 4];
      float q0 = __expf(leakyf(asv.x + adv.x) - m0) * zi0;
      float q1 = __expf(leakyf(asv.y + adv.y) - m1) * zi1;
      float q2 = __expf(leakyf(asv.z + adv.z) - m2) * zi2;
      float q3 = __expf(leakyf(asv.w + adv.w) - m3) * zi3;
      float a = head == 0 ? q0 : (head == 1 ? q1 : (head == 2 ? q2 : q3));
      float4 hv = *(const float4*)&h[(size_t)s * HC + cg4];
      acc.x = fmaf(a, hv.x, acc.x); acc.y = fmaf(a, hv.y, acc.y);
      acc.z = fmaf(a, hv.z, acc.z); acc.w = fmaf(a, hv.w, acc.w);
    }
  }

  if (CONCAT) {
    float4 bb = *(const float4*)&bias[cg4];
    float4 v;
    v.x = fmaxf(acc.x + bb.x, 0.f);
    v.y = fmaxf(acc.y + bb.y, 0.f);
    v.z = fmaxf(acc.z + bb.z, 0.f);
    v.w = fmaxf(acc.w + bb.w, 0.f);
    *(float4*)&out[(size_t)d * HC + cg4] = v;
  } else {
    // mean over heads: sum lanes ^16, ^32
#pragma unroll
    for (int o = 16; o < 64; o <<= 1) {
      acc.x += __shfl_xor(acc.x, o);
      acc.y += __shfl_xor(acc.y, o);
      acc.z += __shfl_xor(acc.z, o);
      acc.w += __shfl_xor(acc.w, o);
    }
    if (lane < 16) {
      int c0 = lane << 2;
      float4 bb = *(const float4*)&bias[c0];
      float4 v;
      v.x = fmaxf(acc.x * 0.25f + bb.x, 0.f);
      v.y = fmaxf(acc.y * 0.25f + bb.y, 0.f);
      v.z = fmaxf(acc.z * 0.25f + bb.z, 0.f);
      v.w = fmaxf(acc.w * 0.25f + bb.w, 0.f);
      *(float4*)&out[(size_t)d * CDIM + c0] = v;
    }
  }
}

// ---------------- global mean pool + final linear ----------------
__device__ inline int lower_bound_i(const int* __restrict__ a, int n, int key) {
  int lo = 0, hi = n;
  while (lo < hi) { int mid = (lo + hi) >> 1; if (a[mid] < key) lo = mid + 1; else hi = mid; }
  return lo;
}

__global__ __launch_bounds__(256) void k_pool(const float* __restrict__ x, const int* __restrict__ batch,
                                              const float* __restrict__ Wl, const float* __restrict__ bl,
                                              float* __restrict__ out) {
  int g = blockIdx.x, tid = threadIdx.x;
  int lo = lower_bound_i(batch, N_NODES, g);
  int hi = lower_bound_i(batch, N_NODES, g + 1);
  int c = tid & 63, sl = tid >> 6;
  float acc = 0.f;
  for (int n = lo + sl; n < hi; n += 4)
    acc += x[(size_t)n * CDIM + c];
  __shared__ float s[256];
  __shared__ float pooled[64];
  s[tid] = acc;
  __syncthreads();
  if (tid < 64) {
    float cnt = fmaxf((float)(hi - lo), 1.f);
    pooled[tid] = (s[tid] + s[tid + 64] + s[tid + 128] + s[tid + 192]) / cnt;
  }
  __syncthreads();
  if (tid < NCLS) {
    float o = bl[tid];
    for (int cc = 0; cc < CDIM; ++cc)
      o = fmaf(pooled[cc], Wl[cc * NCLS + tid], o);
    out[g * NCLS + tid] = o;
  }
}

extern "C" void kernel_launch(void* const* d_in, const int* in_sizes, int n_in,
                              void* d_out, int out_size, void* d_ws, size_t ws_size,
                              hipStream_t stream) {
  const float* x     = (const float*)d_in[0];
  const int*   ei    = (const int*)d_in[1];
  const int*   batch = (const int*)d_in[2];
  const float* W1  = (const float*)d_in[3];
  const float* as1 = (const float*)d_in[4];
  const float* ad1 = (const float*)d_in[5];
  const float* b1  = (const float*)d_in[6];
  const float* W2  = (const float*)d_in[7];
  const float* as2 = (const float*)d_in[8];
  const float* ad2 = (const float*)d_in[9];
  const float* b2  = (const float*)d_in[10];
  const float* W3  = (const float*)d_in[11];
  const float* as3 = (const float*)d_in[12];
  const float* ad3 = (const float*)d_in[13];
  const float* b3  = (const float*)d_in[14];
  const float* Wl  = (const float*)d_in[15];
  const float* bl  = (const float*)d_in[16];
  float* out = (float*)d_out;

  char* ws = (char*)d_ws;
  size_t o = 0;
  auto alloc = [&](size_t bytes) -> void* {
    void* p = ws + o;
    o += (bytes + 255) & ~(size_t)255;
    return p;
  };
  float* bufA  = (float*)alloc((size_t)N_NODES * HC * 4);
  float* bufB  = (float*)alloc((size_t)N_NODES * HC * 4);
  float* al_s  = (float*)alloc((size_t)N_NODES * 4 * 4);
  float* al_d  = (float*)alloc((size_t)N_NODES * 4 * 4);
  int*   deg   = (int*)alloc((size_t)N_NODES * 4);
  int*   off   = (int*)alloc((size_t)(N_NODES + 1) * 4);
  int*   cursor= (int*)alloc((size_t)N_NODES * 4);
  int*   blksum= (int*)alloc(1024);
  int*   csr   = (int*)alloc((size_t)E_TOT * 4);

  int nblk = (N_NODES + 255) / 256;  // 196
  k_init_deg<<<nblk, 256, 0, stream>>>(deg);
  k_hist<<<(E_EDGES + 255) / 256, 256, 0, stream>>>(ei, deg);
  k_scan1<<<nblk, 256, 0, stream>>>(deg, off, blksum);
  k_scan2<<<1, 256, 0, stream>>>(blksum, nblk);
  k_scan3<<<nblk, 256, 0, stream>>>(deg, off, blksum, cursor);
  k_fill<<<(E_TOT + 255) / 256, 256, 0, stream>>>(ei, cursor, csr);

  dim3 ggrid((N_NODES + 63) / 64, HC / 64);
  int nagg = N_NODES / 4;  // 12500
  // conv1
  k_gemm<F_INDIM><<<ggrid, 256, 0, stream>>>(x, W1, bufA);
  k_attn<<<nagg, 256, 0, stream>>>(bufA, as1, ad1, al_s, al_d);
  k_aggregate<true><<<nagg, 256, 0, stream>>>(bufA, off, csr, al_s, al_d, b1, bufB);
  // conv2
  k_gemm<HC><<<ggrid, 256, 0, stream>>>(bufB, W2, bufA);
  k_attn<<<nagg, 256, 0, stream>>>(bufA, as2, ad2, al_s, al_d);
  k_aggregate<true><<<nagg, 256, 0, stream>>>(bufA, off, csr, al_s, al_d, b2, bufB);
  // conv3
  k_gemm<HC><<<ggrid, 256, 0, stream>>>(bufB, W3, bufA);
  k_attn<<<nagg, 256, 0, stream>>>(bufA, as3, ad3, al_s, al_d);
  k_aggregate<false><<<nagg, 256, 0, stream>>>(bufA, off, csr, al_s, al_d, b3, bufB);
  // pool + linear
  k_pool<<<NGRAPH, 256, 0, stream>>>(bufB, batch, Wl, bl, out);
}

// Round 4
// 623.031 us; speedup vs baseline: 1.7438x; 1.2461x over previous
//
#include <hip/hip_runtime.h>
#include <hip/hip_bf16.h>

#define N_NODES 50000
#define E_EDGES 800000
#define E_TOT   (E_EDGES + N_NODES)
#define F_INDIM 128
#define NHEAD   4
#define CDIM    64
#define HC      256
#define NGRAPH  512
#define NCLS    10
#define NEG_SLOPE 0.2f

typedef __attribute__((ext_vector_type(8))) short short8;
typedef __attribute__((ext_vector_type(4))) float f32x4;

__device__ inline float leakyf(float x) { return x > 0.f ? x : NEG_SLOPE * x; }

__device__ inline unsigned short f2bf(float x) {
  __hip_bfloat16 b = __float2bfloat16(x);
  return *reinterpret_cast<unsigned short*>(&b);
}

// ---------------- CSR build ----------------
__global__ __launch_bounds__(256) void k_init_deg(int* __restrict__ deg) {
  int i = blockIdx.x * 256 + threadIdx.x;
  if (i < N_NODES) deg[i] = 1;  // self-loop
}

__global__ __launch_bounds__(256) void k_hist(const int* __restrict__ ei, int* __restrict__ deg) {
  int e = blockIdx.x * 256 + threadIdx.x;
  if (e < E_EDGES) atomicAdd(&deg[ei[E_EDGES + e]], 1);
}

__global__ __launch_bounds__(256) void k_scan1(const int* __restrict__ deg, int* __restrict__ incl,
                                               int* __restrict__ blksum) {
  __shared__ int s[256];
  int tid = threadIdx.x;
  int i = blockIdx.x * 256 + tid;
  int v = (i < N_NODES) ? deg[i] : 0;
  s[tid] = v;
  __syncthreads();
  for (int d = 1; d < 256; d <<= 1) {
    int t = (tid >= d) ? s[tid - d] : 0;
    __syncthreads();
    s[tid] += t;
    __syncthreads();
  }
  if (i < N_NODES) incl[i] = s[tid];
  if (tid == 255) blksum[blockIdx.x] = s[255];
}

__global__ __launch_bounds__(256) void k_scan2(int* __restrict__ blksum, int nblk) {
  __shared__ int s[256];
  int tid = threadIdx.x;
  int v = (tid < nblk) ? blksum[tid] : 0;
  s[tid] = v;
  __syncthreads();
  for (int d = 1; d < 256; d <<= 1) {
    int t = (tid >= d) ? s[tid - d] : 0;
    __syncthreads();
    s[tid] += t;
    __syncthreads();
  }
  if (tid < nblk) blksum[tid] = s[tid] - v;  // exclusive
}

__global__ __launch_bounds__(256) void k_scan3(const int* __restrict__ deg, int* __restrict__ off,
                                               const int* __restrict__ blksum, int* __restrict__ cursor) {
  int i = blockIdx.x * 256 + threadIdx.x;
  if (i < N_NODES) {
    int excl = off[i] - deg[i] + blksum[blockIdx.x];
    off[i] = excl;
    cursor[i] = excl;
  }
  if (i == 0) off[N_NODES] = E_TOT;
}

__global__ __launch_bounds__(256) void k_fill(const int* __restrict__ ei, int* __restrict__ cursor,
                                              int* __restrict__ csr_src) {
  int idx = blockIdx.x * 256 + threadIdx.x;
  if (idx >= E_TOT) return;
  int s, d;
  if (idx < E_EDGES) { s = ei[idx]; d = ei[E_EDGES + idx]; }
  else               { s = idx - E_EDGES; d = s; }
  int pos = atomicAdd(&cursor[d], 1);
  csr_src[pos] = s;
}

// ---------------- conversions ----------------
__global__ __launch_bounds__(256) void k_cvt_x(const float* __restrict__ x, unsigned short* __restrict__ xb) {
  int i = blockIdx.x * 256 + threadIdx.x;  // one float4 per thread
  float4 v = *(const float4*)&x[(size_t)i * 4];
  ushort4 o = make_ushort4(f2bf(v.x), f2bf(v.y), f2bf(v.z), f2bf(v.w));
  *(ushort4*)&xb[(size_t)i * 4] = o;
}

// W [K][256] f32 -> Wt [256][K] bf16
__global__ __launch_bounds__(256) void k_cvt_wt(const float* __restrict__ W, unsigned short* __restrict__ Wt,
                                                int K) {
  int i = blockIdx.x * 256 + threadIdx.x;
  if (i < K * HC) {
    int k = i >> 8, n = i & 255;
    Wt[n * K + k] = f2bf(W[i]);
  }
}

// ---------------- bf16 MFMA GEMM: C[M x 256] = A[M x K](bf16) * Bt[256 x K](bf16)^T ----------------
// 128x128 tile, 4 waves (2x2), per-wave 64x64 via 4x4 mfma_f32_16x16x32_bf16 fragments.
// LDS XOR-swizzle: slot = chunk ^ (row & 7) (16B chunks, 128B rows).
template<int K>
__global__ __launch_bounds__(256) void k_gemm_bf16(const unsigned short* __restrict__ A,
                                                   const unsigned short* __restrict__ Bt,
                                                   float* __restrict__ C) {
  __shared__ unsigned short As[128 * 64];
  __shared__ unsigned short Bs[128 * 64];
  int tid = threadIdx.x;
  int w = tid >> 6, l = tid & 63;
  int wm = w >> 1, wn = w & 1;
  int m0 = blockIdx.x * 128, n0 = blockIdx.y * 128;
  f32x4 acc[4][4] = {};

  int sr = w * 32 + (l >> 3);     // staging row within tile (+ j*8)
  int g8 = l & 7;                 // global 16B chunk within 64-col row
  int slot = g8 ^ (sr & 7);       // swizzled LDS slot ((sr + j*8)&7 == sr&7)
  int fl = l & 15;

  for (int k0 = 0; k0 < K; k0 += 64) {
    uint4 va[4], vb[4];
#pragma unroll
    for (int j = 0; j < 4; ++j) {
      int ar = m0 + sr + j * 8;
      va[j] = (ar < N_NODES) ? *(const uint4*)&A[(size_t)ar * K + k0 + g8 * 8]
                             : make_uint4(0u, 0u, 0u, 0u);
      vb[j] = *(const uint4*)&Bt[(size_t)(n0 + sr + j * 8) * K + k0 + g8 * 8];
    }
    __syncthreads();  // previous iter's readers done before overwrite
#pragma unroll
    for (int j = 0; j < 4; ++j) {
      *(uint4*)&As[(sr + j * 8) * 64 + slot * 8] = va[j];
      *(uint4*)&Bs[(sr + j * 8) * 64 + slot * 8] = vb[j];
    }
    __syncthreads();
#pragma unroll
    for (int kk = 0; kk < 2; ++kk) {
      int sl = ((kk * 4 + (l >> 4)) ^ (l & 7)) * 8;  // row&7 == l&7 for all frags
      short8 af[4], bfr[4];
#pragma unroll
      for (int f = 0; f < 4; ++f) {
        af[f]  = *(const short8*)&As[(wm * 64 + f * 16 + fl) * 64 + sl];
        bfr[f] = *(const short8*)&Bs[(wn * 64 + f * 16 + fl) * 64 + sl];
      }
#pragma unroll
      for (int f = 0; f < 4; ++f)
#pragma unroll
        for (int g = 0; g < 4; ++g)
          acc[f][g] = __builtin_amdgcn_mfma_f32_16x16x32_bf16(af[f], bfr[g], acc[f][g], 0, 0, 0);
    }
  }
  // epilogue: D row = (l>>4)*4 + reg, col = l&15  [verified C/D mapping]
  int cr = (l >> 4) * 4;
#pragma unroll
  for (int f = 0; f < 4; ++f) {
    int mrow = m0 + wm * 64 + f * 16 + cr;
#pragma unroll
    for (int r = 0; r < 4; ++r) {
      if (mrow + r < N_NODES) {
#pragma unroll
        for (int g = 0; g < 4; ++g)
          C[(size_t)(mrow + r) * HC + n0 + wn * 64 + g * 16 + fl] = acc[f][g][r];
      }
    }
  }
}

// ---------------- attention logits: one wave per node ----------------
__global__ __launch_bounds__(256) void k_attn(const float* __restrict__ h,
                                              const float* __restrict__ a_src, const float* __restrict__ a_dst,
                                              float* __restrict__ al_s, float* __restrict__ al_d) {
  int tid = threadIdx.x;
  int lane = tid & 63;
  int n = blockIdx.x * 4 + (tid >> 6);
  float4 v  = *(const float4*)&h[(size_t)n * HC + (lane << 2)];
  float4 as = *(const float4*)&a_src[lane << 2];
  float4 ad = *(const float4*)&a_dst[lane << 2];
  float ps = v.x * as.x + v.y * as.y + v.z * as.z + v.w * as.w;
  float pd = v.x * ad.x + v.y * ad.y + v.z * ad.z + v.w * ad.w;
#pragma unroll
  for (int o = 1; o < 16; o <<= 1) { ps += __shfl_xor(ps, o); pd += __shfl_xor(pd, o); }
  if ((lane & 15) == 0) {
    al_s[n * 4 + (lane >> 4)] = ps;
    al_d[n * 4 + (lane >> 4)] = pd;
  }
}

// ---------------- GAT aggregation: one WAVE per dst node ----------------
// CONCAT=true  -> writes bf16 [d][256] (consumed only by next GEMM)
// CONCAT=false -> writes f32  [d][64]  (head mean, consumed by pool)
template<bool CONCAT>
__global__ __launch_bounds__(256) void k_aggregate(
    const float* __restrict__ h, const int* __restrict__ off, const int* __restrict__ csr_src,
    const float* __restrict__ al_s, const float* __restrict__ al_d,
    const float* __restrict__ bias, unsigned short* __restrict__ out_bf, float* __restrict__ out_f) {
  __shared__ float s_alpha[4][64][4];
  __shared__ int   s_src[4][64];
  int tid = threadIdx.x;
  int wv = tid >> 6;
  int lane = tid & 63;
  int head = lane >> 4;
  int d = blockIdx.x * 4 + wv;

  int lo  = off[d];
  int deg = off[d + 1] - lo;

  float4 adv = *(const float4*)&al_d[(size_t)d * 4];

  // pass A: per-lane max over strided edges; cache first edge in regs
  float m0 = -1e30f, m1 = -1e30f, m2 = -1e30f, m3 = -1e30f;
  int s0 = 0;
  float e00 = -1e30f, e01 = -1e30f, e02 = -1e30f, e03 = -1e30f;
  for (int e = lane; e < deg; e += 64) {
    int s = csr_src[lo + e];
    float4 asv = *(const float4*)&al_s[(size_t)s * 4];
    float v0 = leakyf(asv.x + adv.x);
    float v1 = leakyf(asv.y + adv.y);
    float v2 = leakyf(asv.z + adv.z);
    float v3 = leakyf(asv.w + adv.w);
    if (e == lane) { s0 = s; e00 = v0; e01 = v1; e02 = v2; e03 = v3; }
    m0 = fmaxf(m0, v0); m1 = fmaxf(m1, v1); m2 = fmaxf(m2, v2); m3 = fmaxf(m3, v3);
  }
#pragma unroll
  for (int o = 1; o < 64; o <<= 1) {
    m0 = fmaxf(m0, __shfl_xor(m0, o));
    m1 = fmaxf(m1, __shfl_xor(m1, o));
    m2 = fmaxf(m2, __shfl_xor(m2, o));
    m3 = fmaxf(m3, __shfl_xor(m3, o));
  }
  // pass B: sum of exp (first edge from registers; extra edges rare)
  float p00 = 0.f, p01 = 0.f, p02 = 0.f, p03 = 0.f;
  if (lane < deg) {
    p00 = __expf(e00 - m0); p01 = __expf(e01 - m1);
    p02 = __expf(e02 - m2); p03 = __expf(e03 - m3);
  }
  float z0 = p00, z1 = p01, z2 = p02, z3 = p03;
  for (int e = lane + 64; e < deg; e += 64) {  // rare
    int s = csr_src[lo + e];
    float4 asv = *(const float4*)&al_s[(size_t)s * 4];
    z0 += __expf(leakyf(asv.x + adv.x) - m0);
    z1 += __expf(leakyf(asv.y + adv.y) - m1);
    z2 += __expf(leakyf(asv.z + adv.z) - m2);
    z3 += __expf(leakyf(asv.w + adv.w) - m3);
  }
#pragma unroll
  for (int o = 1; o < 64; o <<= 1) {
    z0 += __shfl_xor(z0, o); z1 += __shfl_xor(z1, o);
    z2 += __shfl_xor(z2, o); z3 += __shfl_xor(z3, o);
  }
  float zi0 = 1.f / (z0 + 1e-16f), zi1 = 1.f / (z1 + 1e-16f);
  float zi2 = 1.f / (z2 + 1e-16f), zi3 = 1.f / (z3 + 1e-16f);

  s_alpha[wv][lane][0] = p00 * zi0;
  s_alpha[wv][lane][1] = p01 * zi1;
  s_alpha[wv][lane][2] = p02 * zi2;
  s_alpha[wv][lane][3] = p03 * zi3;
  s_src[wv][lane] = s0;
  __syncthreads();

  // phase 3: gather with 8 loads in flight
  int cg4 = lane << 2;
  int dcap = min(deg, 64);
  float4 acc = make_float4(0.f, 0.f, 0.f, 0.f);
  int e = 0;
  for (; e + 8 <= dcap; e += 8) {
    float av[8];
    float4 hv[8];
#pragma unroll
    for (int q = 0; q < 8; ++q) {
      int s = s_src[wv][e + q];
      av[q] = s_alpha[wv][e + q][head];
      hv[q] = *(const float4*)&h[(size_t)s * HC + cg4];
    }
#pragma unroll
    for (int q = 0; q < 8; ++q) {
      acc.x = fmaf(av[q], hv[q].x, acc.x);
      acc.y = fmaf(av[q], hv[q].y, acc.y);
      acc.z = fmaf(av[q], hv[q].z, acc.z);
      acc.w = fmaf(av[q], hv[q].w, acc.w);
    }
  }
  for (; e < dcap; ++e) {
    int s = s_src[wv][e];
    float a = s_alpha[wv][e][head];
    float4 hv = *(const float4*)&h[(size_t)s * HC + cg4];
    acc.x = fmaf(a, hv.x, acc.x); acc.y = fmaf(a, hv.y, acc.y);
    acc.z = fmaf(a, hv.z, acc.z); acc.w = fmaf(a, hv.w, acc.w);
  }
  if (deg > 64) {  // rare slow path: recompute alpha for edges >= 64
    for (int e2 = 64; e2 < deg; ++e2) {
      int s = csr_src[lo + e2];
      float4 asv = *(const float4*)&al_s[(size_t)s * 4];
      float q0 = __expf(leakyf(asv.x + adv.x) - m0) * zi0;
      float q1 = __expf(leakyf(asv.y + adv.y) - m1) * zi1;
      float q2 = __expf(leakyf(asv.z + adv.z) - m2) * zi2;
      float q3 = __expf(leakyf(asv.w + adv.w) - m3) * zi3;
      float a = head == 0 ? q0 : (head == 1 ? q1 : (head == 2 ? q2 : q3));
      float4 hv = *(const float4*)&h[(size_t)s * HC + cg4];
      acc.x = fmaf(a, hv.x, acc.x); acc.y = fmaf(a, hv.y, acc.y);
      acc.z = fmaf(a, hv.z, acc.z); acc.w = fmaf(a, hv.w, acc.w);
    }
  }

  if (CONCAT) {
    float4 bb = *(const float4*)&bias[cg4];
    float vx = fmaxf(acc.x + bb.x, 0.f);
    float vy = fmaxf(acc.y + bb.y, 0.f);
    float vz = fmaxf(acc.z + bb.z, 0.f);
    float vw = fmaxf(acc.w + bb.w, 0.f);
    ushort4 o = make_ushort4(f2bf(vx), f2bf(vy), f2bf(vz), f2bf(vw));
    *(ushort4*)&out_bf[(size_t)d * HC + cg4] = o;
  } else {
    // mean over heads: sum lanes ^16, ^32
#pragma unroll
    for (int o = 16; o < 64; o <<= 1) {
      acc.x += __shfl_xor(acc.x, o);
      acc.y += __shfl_xor(acc.y, o);
      acc.z += __shfl_xor(acc.z, o);
      acc.w += __shfl_xor(acc.w, o);
    }
    if (lane < 16) {
      int c0 = lane << 2;
      float4 bb = *(const float4*)&bias[c0];
      float4 v;
      v.x = fmaxf(acc.x * 0.25f + bb.x, 0.f);
      v.y = fmaxf(acc.y * 0.25f + bb.y, 0.f);
      v.z = fmaxf(acc.z * 0.25f + bb.z, 0.f);
      v.w = fmaxf(acc.w * 0.25f + bb.w, 0.f);
      *(float4*)&out_f[(size_t)d * CDIM + c0] = v;
    }
  }
}

// ---------------- global mean pool + final linear ----------------
__device__ inline int lower_bound_i(const int* __restrict__ a, int n, int key) {
  int lo = 0, hi = n;
  while (lo < hi) { int mid = (lo + hi) >> 1; if (a[mid] < key) lo = mid + 1; else hi = mid; }
  return lo;
}

__global__ __launch_bounds__(256) void k_pool(const float* __restrict__ x, const int* __restrict__ batch,
                                              const float* __restrict__ Wl, const float* __restrict__ bl,
                                              float* __restrict__ out) {
  int g = blockIdx.x, tid = threadIdx.x;
  int lo = lower_bound_i(batch, N_NODES, g);
  int hi = lower_bound_i(batch, N_NODES, g + 1);
  int c = tid & 63, sl = tid >> 6;
  float acc = 0.f;
  for (int n = lo + sl; n < hi; n += 4)
    acc += x[(size_t)n * CDIM + c];
  __shared__ float s[256];
  __shared__ float pooled[64];
  s[tid] = acc;
  __syncthreads();
  if (tid < 64) {
    float cnt = fmaxf((float)(hi - lo), 1.f);
    pooled[tid] = (s[tid] + s[tid + 64] + s[tid + 128] + s[tid + 192]) / cnt;
  }
  __syncthreads();
  if (tid < NCLS) {
    float o = bl[tid];
    for (int cc = 0; cc < CDIM; ++cc)
      o = fmaf(pooled[cc], Wl[cc * NCLS + tid], o);
    out[g * NCLS + tid] = o;
  }
}

extern "C" void kernel_launch(void* const* d_in, const int* in_sizes, int n_in,
                              void* d_out, int out_size, void* d_ws, size_t ws_size,
                              hipStream_t stream) {
  const float* x     = (const float*)d_in[0];
  const int*   ei    = (const int*)d_in[1];
  const int*   batch = (const int*)d_in[2];
  const float* W1  = (const float*)d_in[3];
  const float* as1 = (const float*)d_in[4];
  const float* ad1 = (const float*)d_in[5];
  const float* b1  = (const float*)d_in[6];
  const float* W2  = (const float*)d_in[7];
  const float* as2 = (const float*)d_in[8];
  const float* ad2 = (const float*)d_in[9];
  const float* b2  = (const float*)d_in[10];
  const float* W3  = (const float*)d_in[11];
  const float* as3 = (const float*)d_in[12];
  const float* ad3 = (const float*)d_in[13];
  const float* b3  = (const float*)d_in[14];
  const float* Wl  = (const float*)d_in[15];
  const float* bl  = (const float*)d_in[16];
  float* out = (float*)d_out;

  char* ws = (char*)d_ws;
  size_t o = 0;
  auto alloc = [&](size_t bytes) -> void* {
    void* p = ws + o;
    o += (bytes + 255) & ~(size_t)255;
    return p;
  };
  float*          bufA  = (float*)alloc((size_t)N_NODES * HC * 4);          // h (f32)
  unsigned short* bufBf = (unsigned short*)alloc((size_t)N_NODES * HC * 2); // agg out (bf16)
  float*          bufC  = (float*)alloc((size_t)N_NODES * CDIM * 4);        // conv3 out (f32)
  unsigned short* x_bf  = (unsigned short*)alloc((size_t)N_NODES * F_INDIM * 2);
  unsigned short* Wt1   = (unsigned short*)alloc((size_t)HC * F_INDIM * 2);
  unsigned short* Wt2   = (unsigned short*)alloc((size_t)HC * HC * 2);
  unsigned short* Wt3   = (unsigned short*)alloc((size_t)HC * HC * 2);
  float* al_s  = (float*)alloc((size_t)N_NODES * 4 * 4);
  float* al_d  = (float*)alloc((size_t)N_NODES * 4 * 4);
  int*   deg   = (int*)alloc((size_t)N_NODES * 4);
  int*   off   = (int*)alloc((size_t)(N_NODES + 1) * 4);
  int*   cursor= (int*)alloc((size_t)N_NODES * 4);
  int*   blksum= (int*)alloc(1024);
  int*   csr   = (int*)alloc((size_t)E_TOT * 4);

  int nblk = (N_NODES + 255) / 256;  // 196
  k_init_deg<<<nblk, 256, 0, stream>>>(deg);
  k_hist<<<(E_EDGES + 255) / 256, 256, 0, stream>>>(ei, deg);
  k_scan1<<<nblk, 256, 0, stream>>>(deg, off, blksum);
  k_scan2<<<1, 256, 0, stream>>>(blksum, nblk);
  k_scan3<<<nblk, 256, 0, stream>>>(deg, off, blksum, cursor);
  k_fill<<<(E_TOT + 255) / 256, 256, 0, stream>>>(ei, cursor, csr);

  // conversions
  k_cvt_x<<<(N_NODES * F_INDIM / 4 + 255) / 256, 256, 0, stream>>>(x, x_bf);
  k_cvt_wt<<<(F_INDIM * HC + 255) / 256, 256, 0, stream>>>(W1, Wt1, F_INDIM);
  k_cvt_wt<<<(HC * HC + 255) / 256, 256, 0, stream>>>(W2, Wt2, HC);
  k_cvt_wt<<<(HC * HC + 255) / 256, 256, 0, stream>>>(W3, Wt3, HC);

  dim3 ggrid((N_NODES + 127) / 128, HC / 128);  // 391 x 2
  int nagg = N_NODES / 4;  // 12500
  // conv1
  k_gemm_bf16<F_INDIM><<<ggrid, 256, 0, stream>>>(x_bf, Wt1, bufA);
  k_attn<<<nagg, 256, 0, stream>>>(bufA, as1, ad1, al_s, al_d);
  k_aggregate<true><<<nagg, 256, 0, stream>>>(bufA, off, csr, al_s, al_d, b1, bufBf, nullptr);
  // conv2
  k_gemm_bf16<HC><<<ggrid, 256, 0, stream>>>(bufBf, Wt2, bufA);
  k_attn<<<nagg, 256, 0, stream>>>(bufA, as2, ad2, al_s, al_d);
  k_aggregate<true><<<nagg, 256, 0, stream>>>(bufA, off, csr, al_s, al_d, b2, bufBf, nullptr);
  // conv3
  k_gemm_bf16<HC><<<ggrid, 256, 0, stream>>>(bufBf, Wt3, bufA);
  k_attn<<<nagg, 256, 0, stream>>>(bufA, as3, ad3, al_s, al_d);
  k_aggregate<false><<<nagg, 256, 0, stream>>>(bufA, off, csr, al_s, al_d, b3, nullptr, bufC);
  // pool + linear
  k_pool<<<NGRAPH, 256, 0, stream>>>(bufC, batch, Wl, bl, out);
}

// Round 5
// 453.199 us; speedup vs baseline: 2.3973x; 1.3747x over previous
//
#include <hip/hip_runtime.h>

#define N_NODES 50000
#define E_EDGES 800000
#define E_TOT   (E_EDGES + N_NODES)
#define F_INDIM 128
#define NHEAD   4
#define CDIM    64
#define HC      256
#define NGRAPH  512
#define NCLS    10
#define NEG_SLOPE 0.2f

typedef __attribute__((ext_vector_type(8))) _Float16 f16x8;
typedef __attribute__((ext_vector_type(8))) unsigned short ushort8;
typedef __attribute__((ext_vector_type(4))) float f32x4;

__device__ inline float leakyf(float x) { return x > 0.f ? x : NEG_SLOPE * x; }
__device__ inline unsigned short f2h(float x) {
  _Float16 h = (_Float16)x;
  return __builtin_bit_cast(unsigned short, h);
}
__device__ inline float h2f(unsigned short u) {
  return (float)__builtin_bit_cast(_Float16, u);
}

// ---------------- CSR build ----------------
__global__ __launch_bounds__(256) void k_init_deg(int* __restrict__ deg) {
  int i = blockIdx.x * 256 + threadIdx.x;
  if (i < N_NODES) deg[i] = 1;  // self-loop
}

__global__ __launch_bounds__(256) void k_hist(const int* __restrict__ ei, int* __restrict__ deg) {
  int e = blockIdx.x * 256 + threadIdx.x;
  if (e < E_EDGES) atomicAdd(&deg[ei[E_EDGES + e]], 1);
}

__global__ __launch_bounds__(256) void k_scan1(const int* __restrict__ deg, int* __restrict__ incl,
                                               int* __restrict__ blksum) {
  __shared__ int s[256];
  int tid = threadIdx.x;
  int i = blockIdx.x * 256 + tid;
  int v = (i < N_NODES) ? deg[i] : 0;
  s[tid] = v;
  __syncthreads();
  for (int d = 1; d < 256; d <<= 1) {
    int t = (tid >= d) ? s[tid - d] : 0;
    __syncthreads();
    s[tid] += t;
    __syncthreads();
  }
  if (i < N_NODES) incl[i] = s[tid];
  if (tid == 255) blksum[blockIdx.x] = s[255];
}

__global__ __launch_bounds__(256) void k_scan2(int* __restrict__ blksum, int nblk) {
  __shared__ int s[256];
  int tid = threadIdx.x;
  int v = (tid < nblk) ? blksum[tid] : 0;
  s[tid] = v;
  __syncthreads();
  for (int d = 1; d < 256; d <<= 1) {
    int t = (tid >= d) ? s[tid - d] : 0;
    __syncthreads();
    s[tid] += t;
    __syncthreads();
  }
  if (tid < nblk) blksum[tid] = s[tid] - v;  // exclusive
}

__global__ __launch_bounds__(256) void k_scan3(const int* __restrict__ deg, int* __restrict__ off,
                                               const int* __restrict__ blksum, int* __restrict__ cursor) {
  int i = blockIdx.x * 256 + threadIdx.x;
  if (i < N_NODES) {
    int excl = off[i] - deg[i] + blksum[blockIdx.x];
    off[i] = excl;
    cursor[i] = excl;
  }
  if (i == 0) off[N_NODES] = E_TOT;
}

__global__ __launch_bounds__(256) void k_fill(const int* __restrict__ ei, int* __restrict__ cursor,
                                              int* __restrict__ csr_src) {
  int idx = blockIdx.x * 256 + threadIdx.x;
  if (idx >= E_TOT) return;
  int s, d;
  if (idx < E_EDGES) { s = ei[idx]; d = ei[E_EDGES + idx]; }
  else               { s = idx - E_EDGES; d = s; }
  int pos = atomicAdd(&cursor[d], 1);
  csr_src[pos] = s;
}

// ---------------- conversions ----------------
__global__ __launch_bounds__(256) void k_cvt_x(const float* __restrict__ x, unsigned short* __restrict__ xh) {
  int i = blockIdx.x * 256 + threadIdx.x;  // 8 elements per thread
  float4 v0 = *(const float4*)&x[(size_t)i * 8];
  float4 v1 = *(const float4*)&x[(size_t)i * 8 + 4];
  ushort8 o;
  o[0] = f2h(v0.x); o[1] = f2h(v0.y); o[2] = f2h(v0.z); o[3] = f2h(v0.w);
  o[4] = f2h(v1.x); o[5] = f2h(v1.y); o[6] = f2h(v1.z); o[7] = f2h(v1.w);
  *(ushort8*)&xh[(size_t)i * 8] = o;
}

// W [K][256] f32 -> Wt [256][K] fp16
__global__ __launch_bounds__(256) void k_cvt_wt(const float* __restrict__ W, unsigned short* __restrict__ Wt,
                                                int K) {
  int i = blockIdx.x * 256 + threadIdx.x;
  if (i < K * HC) {
    int k = i >> 8, n = i & 255;
    Wt[n * K + k] = f2h(W[i]);
  }
}

// ---------------- fp16 MFMA GEMM: C[M x 256] = A[M x K](f16) * Bt[256 x K](f16)^T, out fp16 ----------------
// 128x128 tile, 4 waves (2x2), per-wave 64x64 via 4x4 mfma_f32_16x16x32_f16 fragments.
// LDS XOR-swizzle: slot = chunk ^ (row & 7) (16B chunks, 128B rows).
template<int K>
__global__ __launch_bounds__(256) void k_gemm_f16(const unsigned short* __restrict__ A,
                                                  const unsigned short* __restrict__ Bt,
                                                  unsigned short* __restrict__ C) {
  __shared__ unsigned short As[128 * 64];
  __shared__ unsigned short Bs[128 * 64];
  int tid = threadIdx.x;
  int w = tid >> 6, l = tid & 63;
  int wm = w >> 1, wn = w & 1;
  int m0 = blockIdx.x * 128, n0 = blockIdx.y * 128;
  f32x4 acc[4][4] = {};

  int sr = w * 32 + (l >> 3);     // staging row within tile (+ j*8)
  int g8 = l & 7;                 // 16B chunk within 64-col row
  int slot = g8 ^ (sr & 7);       // swizzled LDS slot
  int fl = l & 15;

  for (int k0 = 0; k0 < K; k0 += 64) {
    uint4 va[4], vb[4];
#pragma unroll
    for (int j = 0; j < 4; ++j) {
      int ar = m0 + sr + j * 8;
      va[j] = (ar < N_NODES) ? *(const uint4*)&A[(size_t)ar * K + k0 + g8 * 8]
                             : make_uint4(0u, 0u, 0u, 0u);
      vb[j] = *(const uint4*)&Bt[(size_t)(n0 + sr + j * 8) * K + k0 + g8 * 8];
    }
    __syncthreads();
#pragma unroll
    for (int j = 0; j < 4; ++j) {
      *(uint4*)&As[(sr + j * 8) * 64 + slot * 8] = va[j];
      *(uint4*)&Bs[(sr + j * 8) * 64 + slot * 8] = vb[j];
    }
    __syncthreads();
#pragma unroll
    for (int kk = 0; kk < 2; ++kk) {
      int sl = ((kk * 4 + (l >> 4)) ^ (l & 7)) * 8;
      f16x8 af[4], bfr[4];
#pragma unroll
      for (int f = 0; f < 4; ++f) {
        af[f]  = *(const f16x8*)&As[(wm * 64 + f * 16 + fl) * 64 + sl];
        bfr[f] = *(const f16x8*)&Bs[(wn * 64 + f * 16 + fl) * 64 + sl];
      }
#pragma unroll
      for (int f = 0; f < 4; ++f)
#pragma unroll
        for (int g = 0; g < 4; ++g)
          acc[f][g] = __builtin_amdgcn_mfma_f32_16x16x32_f16(af[f], bfr[g], acc[f][g], 0, 0, 0);
    }
  }
  // epilogue: D row = (l>>4)*4 + reg, col = l&15
  int cr = (l >> 4) * 4;
#pragma unroll
  for (int f = 0; f < 4; ++f) {
    int mrow = m0 + wm * 64 + f * 16 + cr;
#pragma unroll
    for (int r = 0; r < 4; ++r) {
      if (mrow + r < N_NODES) {
#pragma unroll
        for (int g = 0; g < 4; ++g)
          C[(size_t)(mrow + r) * HC + n0 + wn * 64 + g * 16 + fl] = f2h(acc[f][g][r]);
      }
    }
  }
}

// ---------------- attention logits (fp16 h): 2 nodes per wave ----------------
__global__ __launch_bounds__(256) void k_attn(const unsigned short* __restrict__ h,
                                              const float* __restrict__ a_src, const float* __restrict__ a_dst,
                                              float* __restrict__ al_s, float* __restrict__ al_d) {
  int tid = threadIdx.x;
  int lane = tid & 63;
  int n = blockIdx.x * 8 + (tid >> 6) * 2 + (lane >> 5);
  int cg8 = (lane & 31) << 3;
  ushort8 hv = *(const ushort8*)&h[(size_t)n * HC + cg8];
  float4 s0 = *(const float4*)&a_src[cg8], s1 = *(const float4*)&a_src[cg8 + 4];
  float4 d0 = *(const float4*)&a_dst[cg8], d1 = *(const float4*)&a_dst[cg8 + 4];
  float hr[8];
#pragma unroll
  for (int i = 0; i < 8; ++i) hr[i] = h2f(hv[i]);
  float ps = hr[0] * s0.x + hr[1] * s0.y + hr[2] * s0.z + hr[3] * s0.w
           + hr[4] * s1.x + hr[5] * s1.y + hr[6] * s1.z + hr[7] * s1.w;
  float pd = hr[0] * d0.x + hr[1] * d0.y + hr[2] * d0.z + hr[3] * d0.w
           + hr[4] * d1.x + hr[5] * d1.y + hr[6] * d1.z + hr[7] * d1.w;
#pragma unroll
  for (int o = 1; o < 8; o <<= 1) { ps += __shfl_xor(ps, o); pd += __shfl_xor(pd, o); }
  if ((lane & 7) == 0) {
    int head = (lane & 31) >> 3;
    al_s[n * 4 + head] = ps;
    al_d[n * 4 + head] = pd;
  }
}

// ---------------- GAT aggregation: one WAVE per dst node, fp16 gather ----------------
// Gather: lane covers 8 channels (16B); half-wave 0 takes even edge slots, half 1 odd.
// CONCAT=true  -> writes fp16 [d][256] (next GEMM input)
// CONCAT=false -> writes f32  [d][64]  (head mean, pool input)
template<bool CONCAT>
__global__ __launch_bounds__(256) void k_aggregate(
    const unsigned short* __restrict__ h, const int* __restrict__ off, const int* __restrict__ csr_src,
    const float* __restrict__ al_s, const float* __restrict__ al_d,
    const float* __restrict__ bias, unsigned short* __restrict__ out_h, float* __restrict__ out_f) {
  __shared__ float s_alpha[4][64][4];
  __shared__ int   s_src[4][64];
  int tid = threadIdx.x;
  int wv = tid >> 6;
  int lane = tid & 63;
  int half_id = lane >> 5;
  int c8 = lane & 31;
  int cg8 = c8 << 3;
  int head = c8 >> 3;
  int d = blockIdx.x * 4 + wv;

  int lo  = off[d];
  int deg = off[d + 1] - lo;

  float4 adv = *(const float4*)&al_d[(size_t)d * 4];

  // pass A: per-lane max over strided edges; cache first edge in regs
  float m0 = -1e30f, m1 = -1e30f, m2 = -1e30f, m3 = -1e30f;
  int s0 = 0;
  float e00 = -1e30f, e01 = -1e30f, e02 = -1e30f, e03 = -1e30f;
  for (int e = lane; e < deg; e += 64) {
    int s = csr_src[lo + e];
    float4 asv = *(const float4*)&al_s[(size_t)s * 4];
    float v0 = leakyf(asv.x + adv.x);
    float v1 = leakyf(asv.y + adv.y);
    float v2 = leakyf(asv.z + adv.z);
    float v3 = leakyf(asv.w + adv.w);
    if (e == lane) { s0 = s; e00 = v0; e01 = v1; e02 = v2; e03 = v3; }
    m0 = fmaxf(m0, v0); m1 = fmaxf(m1, v1); m2 = fmaxf(m2, v2); m3 = fmaxf(m3, v3);
  }
#pragma unroll
  for (int o = 1; o < 64; o <<= 1) {
    m0 = fmaxf(m0, __shfl_xor(m0, o));
    m1 = fmaxf(m1, __shfl_xor(m1, o));
    m2 = fmaxf(m2, __shfl_xor(m2, o));
    m3 = fmaxf(m3, __shfl_xor(m3, o));
  }
  // pass B: sum of exp
  float p00 = 0.f, p01 = 0.f, p02 = 0.f, p03 = 0.f;
  if (lane < deg) {
    p00 = __expf(e00 - m0); p01 = __expf(e01 - m1);
    p02 = __expf(e02 - m2); p03 = __expf(e03 - m3);
  }
  float z0 = p00, z1 = p01, z2 = p02, z3 = p03;
  for (int e = lane + 64; e < deg; e += 64) {  // rare
    int s = csr_src[lo + e];
    float4 asv = *(const float4*)&al_s[(size_t)s * 4];
    z0 += __expf(leakyf(asv.x + adv.x) - m0);
    z1 += __expf(leakyf(asv.y + adv.y) - m1);
    z2 += __expf(leakyf(asv.z + adv.z) - m2);
    z3 += __expf(leakyf(asv.w + adv.w) - m3);
  }
#pragma unroll
  for (int o = 1; o < 64; o <<= 1) {
    z0 += __shfl_xor(z0, o); z1 += __shfl_xor(z1, o);
    z2 += __shfl_xor(z2, o); z3 += __shfl_xor(z3, o);
  }
  float zi0 = 1.f / (z0 + 1e-16f), zi1 = 1.f / (z1 + 1e-16f);
  float zi2 = 1.f / (z2 + 1e-16f), zi3 = 1.f / (z3 + 1e-16f);

  s_alpha[wv][lane][0] = p00 * zi0;
  s_alpha[wv][lane][1] = p01 * zi1;
  s_alpha[wv][lane][2] = p02 * zi2;
  s_alpha[wv][lane][3] = p03 * zi3;
  s_src[wv][lane] = s0;
  __syncthreads();

  // phase 3: fp16 gather, 2 edges per wave-load, unrolled 4 deep per half-wave
  int dcap = min(deg, 64);
  float acc[8] = {};
  int e = half_id;
  for (; e + 6 < dcap; e += 8) {
    int sv[4]; float av[4]; ushort8 hv[4];
#pragma unroll
    for (int q = 0; q < 4; ++q) {
      int ee = e + q * 2;
      sv[q] = s_src[wv][ee];
      av[q] = s_alpha[wv][ee][head];
    }
#pragma unroll
    for (int q = 0; q < 4; ++q) hv[q] = *(const ushort8*)&h[(size_t)sv[q] * HC + cg8];
#pragma unroll
    for (int q = 0; q < 4; ++q)
#pragma unroll
      for (int i = 0; i < 8; ++i) acc[i] = fmaf(av[q], h2f(hv[q][i]), acc[i]);
  }
  for (; e < dcap; e += 2) {
    int s = s_src[wv][e];
    float a = s_alpha[wv][e][head];
    ushort8 hv = *(const ushort8*)&h[(size_t)s * HC + cg8];
#pragma unroll
    for (int i = 0; i < 8; ++i) acc[i] = fmaf(a, h2f(hv[i]), acc[i]);
  }
  if (deg > 64) {  // rare slow path: recompute alpha for edges >= 64
    for (int e2 = 64 + half_id; e2 < deg; e2 += 2) {
      int s = csr_src[lo + e2];
      float4 asv = *(const float4*)&al_s[(size_t)s * 4];
      float q0 = __expf(leakyf(asv.x + adv.x) - m0) * zi0;
      float q1 = __expf(leakyf(asv.y + adv.y) - m1) * zi1;
      float q2 = __expf(leakyf(asv.z + adv.z) - m2) * zi2;
      float q3 = __expf(leakyf(asv.w + adv.w) - m3) * zi3;
      float a = head == 0 ? q0 : (head == 1 ? q1 : (head == 2 ? q2 : q3));
      ushort8 hv = *(const ushort8*)&h[(size_t)s * HC + cg8];
#pragma unroll
      for (int i = 0; i < 8; ++i) acc[i] = fmaf(a, h2f(hv[i]), acc[i]);
    }
  }

  // combine the two half-wave edge partitions
#pragma unroll
  for (int i = 0; i < 8; ++i) acc[i] += __shfl_xor(acc[i], 32);

  if (CONCAT) {
    if (lane < 32) {
      float4 b0 = *(const float4*)&bias[cg8];
      float4 b1v = *(const float4*)&bias[cg8 + 4];
      ushort8 o;
      o[0] = f2h(fmaxf(acc[0] + b0.x, 0.f));
      o[1] = f2h(fmaxf(acc[1] + b0.y, 0.f));
      o[2] = f2h(fmaxf(acc[2] + b0.z, 0.f));
      o[3] = f2h(fmaxf(acc[3] + b0.w, 0.f));
      o[4] = f2h(fmaxf(acc[4] + b1v.x, 0.f));
      o[5] = f2h(fmaxf(acc[5] + b1v.y, 0.f));
      o[6] = f2h(fmaxf(acc[6] + b1v.z, 0.f));
      o[7] = f2h(fmaxf(acc[7] + b1v.w, 0.f));
      *(ushort8*)&out_h[(size_t)d * HC + cg8] = o;
    }
  } else {
    // mean over heads: heads live at lanes c8, c8+8, c8+16, c8+24 (same channel offset)
#pragma unroll
    for (int i = 0; i < 8; ++i) {
      acc[i] += __shfl_xor(acc[i], 8);
      acc[i] += __shfl_xor(acc[i], 16);
    }
    if (lane < 8) {
      int c0 = lane << 3;
      float4 bb0 = *(const float4*)&bias[c0];
      float4 bb1 = *(const float4*)&bias[c0 + 4];
      float4 v0, v1;
      v0.x = fmaxf(acc[0] * 0.25f + bb0.x, 0.f);
      v0.y = fmaxf(acc[1] * 0.25f + bb0.y, 0.f);
      v0.z = fmaxf(acc[2] * 0.25f + bb0.z, 0.f);
      v0.w = fmaxf(acc[3] * 0.25f + bb0.w, 0.f);
      v1.x = fmaxf(acc[4] * 0.25f + bb1.x, 0.f);
      v1.y = fmaxf(acc[5] * 0.25f + bb1.y, 0.f);
      v1.z = fmaxf(acc[6] * 0.25f + bb1.z, 0.f);
      v1.w = fmaxf(acc[7] * 0.25f + bb1.w, 0.f);
      *(float4*)&out_f[(size_t)d * CDIM + c0] = v0;
      *(float4*)&out_f[(size_t)d * CDIM + c0 + 4] = v1;
    }
  }
}

// ---------------- global mean pool + final linear ----------------
__device__ inline int lower_bound_i(const int* __restrict__ a, int n, int key) {
  int lo = 0, hi = n;
  while (lo < hi) { int mid = (lo + hi) >> 1; if (a[mid] < key) lo = mid + 1; else hi = mid; }
  return lo;
}

__global__ __launch_bounds__(256) void k_pool(const float* __restrict__ x, const int* __restrict__ batch,
                                              const float* __restrict__ Wl, const float* __restrict__ bl,
                                              float* __restrict__ out) {
  int g = blockIdx.x, tid = threadIdx.x;
  int lo = lower_bound_i(batch, N_NODES, g);
  int hi = lower_bound_i(batch, N_NODES, g + 1);
  int c = tid & 63, sl = tid >> 6;
  float acc = 0.f;
  for (int n = lo + sl; n < hi; n += 4)
    acc += x[(size_t)n * CDIM + c];
  __shared__ float s[256];
  __shared__ float pooled[64];
  s[tid] = acc;
  __syncthreads();
  if (tid < 64) {
    float cnt = fmaxf((float)(hi - lo), 1.f);
    pooled[tid] = (s[tid] + s[tid + 64] + s[tid + 128] + s[tid + 192]) / cnt;
  }
  __syncthreads();
  if (tid < NCLS) {
    float o = bl[tid];
    for (int cc = 0; cc < CDIM; ++cc)
      o = fmaf(pooled[cc], Wl[cc * NCLS + tid], o);
    out[g * NCLS + tid] = o;
  }
}

extern "C" void kernel_launch(void* const* d_in, const int* in_sizes, int n_in,
                              void* d_out, int out_size, void* d_ws, size_t ws_size,
                              hipStream_t stream) {
  const float* x     = (const float*)d_in[0];
  const int*   ei    = (const int*)d_in[1];
  const int*   batch = (const int*)d_in[2];
  const float* W1  = (const float*)d_in[3];
  const float* as1 = (const float*)d_in[4];
  const float* ad1 = (const float*)d_in[5];
  const float* b1  = (const float*)d_in[6];
  const float* W2  = (const float*)d_in[7];
  const float* as2 = (const float*)d_in[8];
  const float* ad2 = (const float*)d_in[9];
  const float* b2  = (const float*)d_in[10];
  const float* W3  = (const float*)d_in[11];
  const float* as3 = (const float*)d_in[12];
  const float* ad3 = (const float*)d_in[13];
  const float* b3  = (const float*)d_in[14];
  const float* Wl  = (const float*)d_in[15];
  const float* bl  = (const float*)d_in[16];
  float* out = (float*)d_out;

  char* ws = (char*)d_ws;
  size_t o = 0;
  auto alloc = [&](size_t bytes) -> void* {
    void* p = ws + o;
    o += (bytes + 255) & ~(size_t)255;
    return p;
  };
  unsigned short* hbuf  = (unsigned short*)alloc((size_t)N_NODES * HC * 2);  // GEMM out h (fp16)
  unsigned short* abuf  = (unsigned short*)alloc((size_t)N_NODES * HC * 2);  // aggregate out (fp16)
  float*          bufC  = (float*)alloc((size_t)N_NODES * CDIM * 4);         // conv3 out (f32)
  unsigned short* x_h   = (unsigned short*)alloc((size_t)N_NODES * F_INDIM * 2);
  unsigned short* Wt1   = (unsigned short*)alloc((size_t)HC * F_INDIM * 2);
  unsigned short* Wt2   = (unsigned short*)alloc((size_t)HC * HC * 2);
  unsigned short* Wt3   = (unsigned short*)alloc((size_t)HC * HC * 2);
  float* al_s  = (float*)alloc((size_t)N_NODES * 4 * 4);
  float* al_d  = (float*)alloc((size_t)N_NODES * 4 * 4);
  int*   deg   = (int*)alloc((size_t)N_NODES * 4);
  int*   off   = (int*)alloc((size_t)(N_NODES + 1) * 4);
  int*   cursor= (int*)alloc((size_t)N_NODES * 4);
  int*   blksum= (int*)alloc(1024);
  int*   csr   = (int*)alloc((size_t)E_TOT * 4);

  int nblk = (N_NODES + 255) / 256;  // 196
  k_init_deg<<<nblk, 256, 0, stream>>>(deg);
  k_hist<<<(E_EDGES + 255) / 256, 256, 0, stream>>>(ei, deg);
  k_scan1<<<nblk, 256, 0, stream>>>(deg, off, blksum);
  k_scan2<<<1, 256, 0, stream>>>(blksum, nblk);
  k_scan3<<<nblk, 256, 0, stream>>>(deg, off, blksum, cursor);
  k_fill<<<(E_TOT + 255) / 256, 256, 0, stream>>>(ei, cursor, csr);

  // conversions
  k_cvt_x<<<(N_NODES * F_INDIM / 8 + 255) / 256, 256, 0, stream>>>(x, x_h);
  k_cvt_wt<<<(F_INDIM * HC + 255) / 256, 256, 0, stream>>>(W1, Wt1, F_INDIM);
  k_cvt_wt<<<(HC * HC + 255) / 256, 256, 0, stream>>>(W2, Wt2, HC);
  k_cvt_wt<<<(HC * HC + 255) / 256, 256, 0, stream>>>(W3, Wt3, HC);

  dim3 ggrid((N_NODES + 127) / 128, HC / 128);  // 391 x 2
  int nagg = N_NODES / 4;   // 12500
  int natt = N_NODES / 8;   // 6250
  // conv1
  k_gemm_f16<F_INDIM><<<ggrid, 256, 0, stream>>>(x_h, Wt1, hbuf);
  k_attn<<<natt, 256, 0, stream>>>(hbuf, as1, ad1, al_s, al_d);
  k_aggregate<true><<<nagg, 256, 0, stream>>>(hbuf, off, csr, al_s, al_d, b1, abuf, nullptr);
  // conv2
  k_gemm_f16<HC><<<ggrid, 256, 0, stream>>>(abuf, Wt2, hbuf);
  k_attn<<<natt, 256, 0, stream>>>(hbuf, as2, ad2, al_s, al_d);
  k_aggregate<true><<<nagg, 256, 0, stream>>>(hbuf, off, csr, al_s, al_d, b2, abuf, nullptr);
  // conv3
  k_gemm_f16<HC><<<ggrid, 256, 0, stream>>>(abuf, Wt3, hbuf);
  k_attn<<<natt, 256, 0, stream>>>(hbuf, as3, ad3, al_s, al_d);
  k_aggregate<false><<<nagg, 256, 0, stream>>>(hbuf, off, csr, al_s, al_d, b3, nullptr, bufC);
  // pool + linear
  k_pool<<<NGRAPH, 256, 0, stream>>>(bufC, batch, Wl, bl, out);
}